// Round 2
// baseline (404.743 us; speedup 1.0000x reference)
//
#include <hip/hip_runtime.h>
#include <stdint.h>

// C=32 captions, I=32 images, T=40 words, R=36 regions, D=1024.
// R13: full two-iteration fusion into one attn block per (c,i) pair.
//   - iter-2 S2 = ctx@q2^T accumulated DURING gating: each wave stages its
//     16-d q2 chunk (bf16) in per-wave LDS, MFMAs it against imgb (K=16
//     zero-padded to 32). q2 never touches HBM (-84MB write, -84MB read),
//     attn_k<2> kernel deleted (was ~150us, pure latency).
//   - iter-2 cosine numerator: pn2 = sum_r P2[r,t]*S1[r,t]; S1 kept in LDS
//     from phase 1 (s1raw global buffer deleted). pw2 via same Gram.
//   - sigmoid/tanh via v_rcp_f32 (__builtin_amdgcn_rcpf) - the two
//     full-precision fdivs per element were ~24 VALU instrs, now 2.
//   - preL/preG now fp32 from gemm_w (no bf2f unpack in gating epilogue).

typedef unsigned short u16;
typedef __attribute__((ext_vector_type(8))) short bf16x8;
typedef __attribute__((ext_vector_type(4))) float f32x4;

#define MFMA_BF16(a, b, c) __builtin_amdgcn_mfma_f32_16x16x32_bf16((a), (b), (c), 0, 0, 0)

__device__ __forceinline__ float bf2f(u16 u) {
  union { unsigned v; float f; } x; x.v = ((unsigned)u) << 16; return x.f;
}
__device__ __forceinline__ u16 f2bf(float f) {  // round-to-nearest-even
  union { float f; unsigned v; } x; x.f = f;
  return (u16)((x.v + 0x7fffu + ((x.v >> 16) & 1u)) >> 16);
}
__device__ __forceinline__ float frcp(float x) { return __builtin_amdgcn_rcpf(x); }
// async 16B global->LDS (DMA; LDS dest = wave-uniform base + lane*16)
__device__ __forceinline__ void gl2lds16(const u16* g, u16* l) {
  __builtin_amdgcn_global_load_lds((const __attribute__((address_space(1))) void*)g,
                                   (__attribute__((address_space(3))) void*)l, 16, 0, 0);
}

// ---------------------------------------------------------------------------
__global__ void cvt_k(const float* __restrict__ src, u16* __restrict__ dst) {
  const int idx = (blockIdx.x * 256 + threadIdx.x) * 4;
  const float4 v = *(const float4*)(src + idx);
  u16 o[4] = {f2bf(v.x), f2bf(v.y), f2bf(v.z), f2bf(v.w)};
  *(uint2*)(dst + idx) = *(const uint2*)o;
}

// Build cwT[i][d][40] bf16 from cw fp32 [i*36+r][1024]; r pad 36..39 = 0.
__global__ void cwt_k(const float* __restrict__ cw, u16* __restrict__ cwT) {
  const int g = blockIdx.x * 256 + threadIdx.x;  // i*1024+d
  const int i = g >> 10, d = g & 1023;
  u16 row[40];
#pragma unroll
  for (int r = 0; r < 36; ++r) row[r] = f2bf(cw[((size_t)(i * 36 + r) << 10) + d]);
#pragma unroll
  for (int r = 36; r < 40; ++r) row[r] = 0;
  u16* dst = cwT + (size_t)g * 40;
#pragma unroll
  for (int j = 0; j < 5; ++j) *(uint4*)(dst + j * 8) = *(const uint4*)(row + j * 8);
}

// ---------------------------------------------------------------------------
__global__ void capnorm_k(const float* __restrict__ cap, float* __restrict__ cnorm) {
  const int wv = threadIdx.x >> 6, lane = threadIdx.x & 63;
  const int row = blockIdx.x * 4 + wv;  // < 1280
  const float* p = cap + ((size_t)row << 10) + lane * 16;
  float s = 0.f;
#pragma unroll
  for (int e = 0; e < 16; ++e) { float v = p[e]; s += v * v; }
#pragma unroll
  for (int off = 32; off > 0; off >>= 1) s += __shfl_down(s, off, 64);
  if (lane == 0) cnorm[row] = sqrtf(s);
}

// ---------------------------------------------------------------------------
__global__ void transpose_k(const float* __restrict__ Wl, const float* __restrict__ Wg,
                            u16* __restrict__ WTl, u16* __restrict__ WTg) {
  __shared__ u16 tile[32][33];
  const float* src = blockIdx.z ? Wg : Wl;
  u16* dst = blockIdx.z ? WTg : WTl;
  const int k0 = blockIdx.x * 32, n0 = blockIdx.y * 32;
  const int tx = threadIdx.x, ty = threadIdx.y;
#pragma unroll
  for (int j = 0; j < 4; ++j)
    tile[ty + 8 * j][tx] = f2bf(src[(size_t)(k0 + ty + 8 * j) * 1024 + n0 + tx]);
  __syncthreads();
#pragma unroll
  for (int j = 0; j < 4; ++j)
    dst[(size_t)(n0 + ty + 8 * j) * 2048 + k0 + tx] = tile[tx][ty + 8 * j];
}

// ---------------------------------------------------------------------------
// Dual-B GEMM: out{L,G}[m,n] = sum_k A[m,k]*W{l,g}[kofs+k][n], K=1024, fp32 out.
template <int IMGW>
__global__ __launch_bounds__(256, 2) void gemm_w(
    const u16* __restrict__ A, const u16* __restrict__ WTl, const u16* __restrict__ WTg,
    float* __restrict__ outL, float* __restrict__ outG) {
  __shared__ __align__(16) u16 lsA[128 * 32];
  __shared__ __align__(16) u16 lsBl[128 * 32];
  __shared__ __align__(16) u16 lsBg[128 * 32];
  const int tid = threadIdx.x;
  const int bm = blockIdx.x >> 3, bn = blockIdx.x & 7;
  const int wv = tid >> 6, lane = tid & 63;
  const int quad = lane >> 4, l15 = lane & 15;
  const int wm = (wv & 1) << 6, wn = (wv >> 1) << 6;
  const int kofs = IMGW ? 1024 : 0;

  f32x4 accL[4][4], accG[4][4];
#pragma unroll
  for (int a = 0; a < 4; ++a)
#pragma unroll
    for (int b = 0; b < 4; ++b) {
      accL[a][b] = (f32x4){0.f, 0.f, 0.f, 0.f};
      accG[a][b] = (f32x4){0.f, 0.f, 0.f, 0.f};
    }

  const size_t arow0 = (size_t)bm * 128 * 1024;
  for (int kt = 0; kt < 32; ++kt) {
    if (kt) __syncthreads();
#pragma unroll
    for (int s = 0; s < 2; ++s) {
      const int idx = s * 256 + tid;
      const int row = idx >> 2, c8 = idx & 3;
      gl2lds16(A + arow0 + (size_t)row * 1024 + kt * 32 + c8 * 8,
               lsA + (size_t)(s * 256 + wv * 64) * 8);
      const size_t bro = (size_t)(bn * 128 + row) * 2048 + kofs + kt * 32 + c8 * 8;
      gl2lds16(WTl + bro, lsBl + (size_t)(s * 256 + wv * 64) * 8);
      gl2lds16(WTg + bro, lsBg + (size_t)(s * 256 + wv * 64) * 8);
    }
    __syncthreads();
    bf16x8 af[4], bl8[4], bg8[4];
#pragma unroll
    for (int mt = 0; mt < 4; ++mt)
      af[mt] = *(const bf16x8*)(lsA + (wm + mt * 16 + l15) * 32 + quad * 8);
#pragma unroll
    for (int nt = 0; nt < 4; ++nt) {
      bl8[nt] = *(const bf16x8*)(lsBl + (wn + nt * 16 + l15) * 32 + quad * 8);
      bg8[nt] = *(const bf16x8*)(lsBg + (wn + nt * 16 + l15) * 32 + quad * 8);
    }
#pragma unroll
    for (int mt = 0; mt < 4; ++mt)
#pragma unroll
      for (int nt = 0; nt < 4; ++nt) {
        accL[mt][nt] = MFMA_BF16(af[mt], bl8[nt], accL[mt][nt]);
        accG[mt][nt] = MFMA_BF16(af[mt], bg8[nt], accG[mt][nt]);
      }
  }
#pragma unroll
  for (int mt = 0; mt < 4; ++mt)
#pragma unroll
    for (int nt = 0; nt < 4; ++nt)
#pragma unroll
      for (int r = 0; r < 4; ++r) {
        const int m = bm * 128 + wm + mt * 16 + quad * 4 + r;
        const int n = bn * 128 + wn + nt * 16 + l15;
        outL[(size_t)m * 1024 + n] = accL[mt][nt][r];
        outG[(size_t)m * 1024 + n] = accG[mt][nt][r];
      }
}

// ---------------------------------------------------------------------------
// Per-image Gram: G[i] = ctx_i @ ctx_i^T [36x36], stored [48][64] bf16 hi+lo.
__global__ __launch_bounds__(256, 2) void gram_k(const u16* __restrict__ imgb,
                                                 u16* __restrict__ Ghi,
                                                 u16* __restrict__ Glo) {
  __shared__ float lsS[48 * 52];
  const int tid = threadIdx.x;
  const int i = blockIdx.x;
  const int wv = tid >> 6, lane = tid & 63;
  const int quad = lane >> 4, l15 = lane & 15;
  for (int k = tid; k < 48 * 52; k += 256) lsS[k] = 0.f;

  const u16* arow[3]; bool avalid[3];
#pragma unroll
  for (int mt = 0; mt < 3; ++mt) {
    const int r = mt * 16 + l15;
    avalid[mt] = r < 36;
    arow[mt] = imgb + ((size_t)(i * 36 + (r < 36 ? r : 35)) << 10);
  }
  const bf16x8 zero8 = {0, 0, 0, 0, 0, 0, 0, 0};
  f32x4 acc[3][3];
#pragma unroll
  for (int a = 0; a < 3; ++a)
#pragma unroll
    for (int b = 0; b < 3; ++b) acc[a][b] = (f32x4){0.f, 0.f, 0.f, 0.f};

  for (int kk = wv * 8; kk < wv * 8 + 8; ++kk) {
    const int ko = kk * 32 + quad * 8;
    bf16x8 af[3];
#pragma unroll
    for (int mt = 0; mt < 3; ++mt)
      af[mt] = avalid[mt] ? *(const bf16x8*)(arow[mt] + ko) : zero8;
#pragma unroll
    for (int mt = 0; mt < 3; ++mt)
#pragma unroll
      for (int nt = 0; nt < 3; ++nt)
        acc[mt][nt] = MFMA_BF16(af[mt], af[nt], acc[mt][nt]);
  }
  __syncthreads();
#pragma unroll
  for (int mt = 0; mt < 3; ++mt)
#pragma unroll
    for (int nt = 0; nt < 3; ++nt)
#pragma unroll
      for (int rg = 0; rg < 4; ++rg)
        atomicAdd(&lsS[(nt * 16 + l15) * 52 + mt * 16 + quad * 4 + rg],
                  acc[mt][nt][rg]);
  __syncthreads();
  if (wv == 0) {
#pragma unroll
    for (int nt = 0; nt < 3; ++nt) {
      const int rp = nt * 16 + l15;  // stored row (G symmetric)
#pragma unroll
      for (int mt = 0; mt < 3; ++mt) {
        const f32x4 g = *(const f32x4*)&lsS[rp * 52 + mt * 16 + quad * 4];
        u16 hv[4], lv[4];
#pragma unroll
        for (int rg = 0; rg < 4; ++rg) {
          hv[rg] = f2bf(g[rg]);
          lv[rg] = f2bf(g[rg] - bf2f(hv[rg]));
        }
        const size_t gb = ((size_t)i * 48 + rp) * 64 + mt * 16 + quad * 4;
        *(uint2*)(Ghi + gb) = *(const uint2*)hv;
        *(uint2*)(Glo + gb) = *(const uint2*)lv;
      }
    }
  }
  for (int k = tid; k < 48 * 16; k += 256) {  // zero cols 48..63
    const size_t gb = ((size_t)i * 48 + (k >> 4)) * 64 + 48 + (k & 15);
    Ghi[gb] = 0; Glo[gb] = 0;
  }
}

// ---------------------------------------------------------------------------
// wave-0 softmax: lsSrc [t][r] f32 stride 52 -> lsP [t][r] bf16 stride 72.
__device__ __forceinline__ void softmax_w(const float* lsSrc, u16* lsP,
                                          int quad, int l15) {
  float sS[3][3][4];
#pragma unroll
  for (int mt = 0; mt < 3; ++mt)
#pragma unroll
    for (int nt = 0; nt < 3; ++nt) {
      const f32x4 v = *(const f32x4*)&lsSrc[(nt * 16 + l15) * 52 + mt * 16 + quad * 4];
#pragma unroll
      for (int rg = 0; rg < 4; ++rg) sS[mt][nt][rg] = v[rg];
    }
  float rn[3][4];
#pragma unroll
  for (int mt = 0; mt < 3; ++mt)
#pragma unroll
    for (int rg = 0; rg < 4; ++rg) {
      float s2 = 0.f;
#pragma unroll
      for (int nt = 0; nt < 3; ++nt) {
        float v = sS[mt][nt][rg]; v = v > 0.f ? v : 0.1f * v; s2 += v * v;
      }
      s2 += __shfl_xor(s2, 1, 64); s2 += __shfl_xor(s2, 2, 64);
      s2 += __shfl_xor(s2, 4, 64); s2 += __shfl_xor(s2, 8, 64);
      rn[mt][rg] = sqrtf(s2) + 1e-8f;
    }
  float mx[3] = {-3.0e38f, -3.0e38f, -3.0e38f};
#pragma unroll
  for (int mt = 0; mt < 3; ++mt)
#pragma unroll
    for (int nt = 0; nt < 3; ++nt)
#pragma unroll
      for (int rg = 0; rg < 4; ++rg) {
        const int r = mt * 16 + quad * 4 + rg;
        float v = sS[mt][nt][rg]; v = v > 0.f ? v : 0.1f * v;
        float zz = 9.f * v / rn[mt][rg];
        zz = (r < 36) ? zz : -3.0e38f;
        sS[mt][nt][rg] = zz;
        mx[nt] = fmaxf(mx[nt], zz);
      }
#pragma unroll
  for (int nt = 0; nt < 3; ++nt) {
    mx[nt] = fmaxf(mx[nt], __shfl_xor(mx[nt], 16, 64));
    mx[nt] = fmaxf(mx[nt], __shfl_xor(mx[nt], 32, 64));
  }
  float ss[3] = {0.f, 0.f, 0.f};
#pragma unroll
  for (int mt = 0; mt < 3; ++mt)
#pragma unroll
    for (int nt = 0; nt < 3; ++nt)
#pragma unroll
      for (int rg = 0; rg < 4; ++rg) {
        const float e = __expf(sS[mt][nt][rg] - mx[nt]);
        sS[mt][nt][rg] = e; ss[nt] += e;
      }
#pragma unroll
  for (int nt = 0; nt < 3; ++nt) {
    ss[nt] += __shfl_xor(ss[nt], 16, 64);
    ss[nt] += __shfl_xor(ss[nt], 32, 64);
    ss[nt] = 1.f / ss[nt];
  }
#pragma unroll
  for (int nt = 0; nt < 3; ++nt) {
    const int t = nt * 16 + l15;
    if (t < 40) {
#pragma unroll
      for (int mt = 0; mt < 3; ++mt) {
        u16 pv[4];
#pragma unroll
        for (int rg = 0; rg < 4; ++rg) pv[rg] = f2bf(sS[mt][nt][rg] * ss[nt]);
        *(uint2*)(lsP + t * 72 + mt * 16 + quad * 4) = *(const uint2*)pv;
      }
    }
  }
}

// wave-1 score: pn = sum_r P*S1 (LDS), pw = P^T G P (Gram MFMA). Returns mean
// cosine (all lanes).
__device__ __forceinline__ float score_w(const u16* lsP, const float* lsS1,
                                         const u16* Ghi, const u16* Glo,
                                         const float* cnorm, int c, int i,
                                         int quad, int l15) {
  float pf[3][3][4];
  float pnv[3] = {0.f, 0.f, 0.f}, pwv[3] = {0.f, 0.f, 0.f};
#pragma unroll
  for (int nt = 0; nt < 3; ++nt) {
    const int t = nt * 16 + l15;
#pragma unroll
    for (int mt = 0; mt < 3; ++mt) {
      const uint2 p2 = *(const uint2*)(lsP + t * 72 + mt * 16 + quad * 4);
      pf[mt][nt][0] = bf2f((u16)(p2.x & 0xffffu));
      pf[mt][nt][1] = bf2f((u16)(p2.x >> 16));
      pf[mt][nt][2] = bf2f((u16)(p2.y & 0xffffu));
      pf[mt][nt][3] = bf2f((u16)(p2.y >> 16));
      const f32x4 s1 = *(const f32x4*)&lsS1[t * 52 + mt * 16 + quad * 4];
#pragma unroll
      for (int rg = 0; rg < 4; ++rg) pnv[nt] += pf[mt][nt][rg] * s1[rg];
    }
  }
  bf16x8 afA[3][2];
#pragma unroll
  for (int mtT = 0; mtT < 3; ++mtT)
#pragma unroll
    for (int ks = 0; ks < 2; ++ks)
      afA[mtT][ks] =
          *(const bf16x8*)(lsP + (mtT * 16 + l15) * 72 + ks * 32 + quad * 8);
  f32x4 gp[3][3];
#pragma unroll
  for (int a = 0; a < 3; ++a)
#pragma unroll
    for (int b = 0; b < 3; ++b) gp[a][b] = (f32x4){0.f, 0.f, 0.f, 0.f};
#pragma unroll
  for (int ks = 0; ks < 2; ++ks)
#pragma unroll
    for (int mtG = 0; mtG < 3; ++mtG) {
      const size_t gb = ((size_t)i * 48 + mtG * 16 + l15) * 64 + ks * 32 + quad * 8;
      const bf16x8 gh = *(const bf16x8*)(Ghi + gb);
      const bf16x8 gl = *(const bf16x8*)(Glo + gb);
#pragma unroll
      for (int mtT = 0; mtT < 3; ++mtT) {
        gp[mtG][mtT] = MFMA_BF16(gh, afA[mtT][ks], gp[mtG][mtT]);
        gp[mtG][mtT] = MFMA_BF16(gl, afA[mtT][ks], gp[mtG][mtT]);
      }
    }
#pragma unroll
  for (int nt = 0; nt < 3; ++nt)
#pragma unroll
    for (int mt = 0; mt < 3; ++mt)
#pragma unroll
      for (int rg = 0; rg < 4; ++rg)
        pwv[nt] += pf[mt][nt][rg] * gp[mt][nt][rg];
#pragma unroll
  for (int nt = 0; nt < 3; ++nt) {
    pnv[nt] += __shfl_xor(pnv[nt], 16, 64); pnv[nt] += __shfl_xor(pnv[nt], 32, 64);
    pwv[nt] += __shfl_xor(pwv[nt], 16, 64); pwv[nt] += __shfl_xor(pwv[nt], 32, 64);
  }
  float tot = 0.f;
#pragma unroll
  for (int nt = 0; nt < 3; ++nt) {
    const int t = nt * 16 + l15;
    if (t < 40) {
      const float w2 = sqrtf(fmaxf(pwv[nt], 0.f));
      tot += pnv[nt] / fmaxf(cnorm[c * 40 + t] * w2, 1e-8f);
    }
  }
  tot += __shfl_xor(tot, 1, 64); tot += __shfl_xor(tot, 2, 64);
  tot += __shfl_xor(tot, 4, 64); tot += __shfl_xor(tot, 8, 64);
  return tot * (1.f / 40.f);
}

// ---------------------------------------------------------------------------
// Fully fused two-iteration attention per (c,i) pair.
__global__ __launch_bounds__(256, 4) void attn_k(
    const u16* __restrict__ imgb, const u16* __restrict__ capb,
    const u16* __restrict__ cwTL, const u16* __restrict__ cwTG,
    const float* __restrict__ preL, const float* __restrict__ preG,
    const float* __restrict__ capf, const float* __restrict__ bL,
    const float* __restrict__ bG, const float* __restrict__ cnorm,
    const u16* __restrict__ Ghi, const u16* __restrict__ Glo,
    float* __restrict__ score) {
  __shared__ __align__(16) u16 lsAT[48 * 72];     // P [t][r] bf16
  __shared__ __align__(16) float lsS[48 * 52];    // S1 [t][r] f32 (persists!)
  __shared__ __align__(16) float lsS2[48 * 52];   // S2 [t][r] f32
  __shared__ __align__(16) u16 lsQ[4 * 48 * 32];  // per-wave q2 chunk [t][16+16pad]

  const int tid = threadIdx.x;
  const int c = blockIdx.x >> 5, i = blockIdx.x & 31;
  const int wv = tid >> 6, lane = tid & 63;
  const int quad = lane >> 4, l15 = lane & 15;

  for (int k = tid; k < 1728; k += 256) ((unsigned*)lsAT)[k] = 0u;
  for (int k = tid; k < 2496; k += 256) lsS[k] = 0.f;
  for (int k = tid; k < 2496; k += 256) lsS2[k] = 0.f;
  for (int k = tid; k < 3072; k += 256) ((unsigned*)lsQ)[k] = 0u;

  const u16* arow[3]; bool avalid[3];
  const u16* brow[3]; bool bvalid[3];
#pragma unroll
  for (int mt = 0; mt < 3; ++mt) {
    const int r = mt * 16 + l15;
    avalid[mt] = r < 36;
    arow[mt] = imgb + ((size_t)(i * 36 + (r < 36 ? r : 35)) << 10);
  }
#pragma unroll
  for (int nt = 0; nt < 3; ++nt) {
    const int t = nt * 16 + l15;
    bvalid[nt] = t < 40;
    brow[nt] = capb + ((size_t)(c * 40 + (t < 40 ? t : 39)) << 10);
  }
  const bf16x8 zero8 = {0, 0, 0, 0, 0, 0, 0, 0};

  // ---- phase 1: partial S1 over this wave's K-range
  f32x4 accS[3][3];
#pragma unroll
  for (int a = 0; a < 3; ++a)
#pragma unroll
    for (int b = 0; b < 3; ++b) accS[a][b] = (f32x4){0.f, 0.f, 0.f, 0.f};

  for (int kk = wv * 8; kk < wv * 8 + 8; ++kk) {
    const int ko = kk * 32 + quad * 8;
    bf16x8 af[3], bq[3];
#pragma unroll
    for (int mt = 0; mt < 3; ++mt)
      af[mt] = avalid[mt] ? *(const bf16x8*)(arow[mt] + ko) : zero8;
#pragma unroll
    for (int nt = 0; nt < 3; ++nt)
      bq[nt] = bvalid[nt] ? *(const bf16x8*)(brow[nt] + ko) : zero8;
#pragma unroll
    for (int mt = 0; mt < 3; ++mt)
#pragma unroll
      for (int nt = 0; nt < 3; ++nt)
        accS[mt][nt] = MFMA_BF16(af[mt], bq[nt], accS[mt][nt]);
  }
  __syncthreads();  // zeros visible
#pragma unroll
  for (int mt = 0; mt < 3; ++mt)
#pragma unroll
    for (int nt = 0; nt < 3; ++nt)
#pragma unroll
      for (int rg = 0; rg < 4; ++rg)
        atomicAdd(&lsS[(nt * 16 + l15) * 52 + mt * 16 + quad * 4 + rg],
                  accS[mt][nt][rg]);
  __syncthreads();

  if (wv == 0) softmax_w(lsS, lsAT, quad, l15);
  __syncthreads();

  float sim = 0.f;
  if (wv == 1) sim = score_w(lsAT, lsS, Ghi, Glo, cnorm, c, i, quad, l15);

  // ---- gating + fused S2 = ctx@q2^T over this wave's d-range
  f32x4 accS2[3][3];
#pragma unroll
  for (int a = 0; a < 3; ++a)
#pragma unroll
    for (int b = 0; b < 3; ++b) accS2[a][b] = (f32x4){0.f, 0.f, 0.f, 0.f};
  u16* lsQw = lsQ + wv * 48 * 32;
  const int dbase = wv * 256;

  for (int nt2 = 0; nt2 < 16; ++nt2) {
    const int d0 = dbase + nt2 * 16;
    const u16* cwl = cwTL + ((size_t)(i << 10) + d0 + l15) * 40;
    const u16* cwg = cwTG + ((size_t)(i << 10) + d0 + l15) * 40;
    const bf16x8 cl0 = *(const bf16x8*)(cwl + quad * 8);
    const bf16x8 cl1 = *(const bf16x8*)(cwl + 32 + quad * 8);  // overrun: P=0 there
    const bf16x8 cg0 = *(const bf16x8*)(cwg + quad * 8);
    const bf16x8 cg1 = *(const bf16x8*)(cwg + 32 + quad * 8);
    const f32x4 bl4 = *(const f32x4*)(bL + d0 + quad * 4);
    const f32x4 bg4 = *(const f32x4*)(bG + d0 + quad * 4);
#pragma unroll
    for (int mtT = 0; mtT < 3; ++mtT) {
      const bf16x8 pa0 = *(const bf16x8*)(lsAT + (mtT * 16 + l15) * 72 + quad * 8);
      const bf16x8 pa1 = *(const bf16x8*)(lsAT + (mtT * 16 + l15) * 72 + 32 + quad * 8);
      f32x4 zL = (f32x4){0.f, 0.f, 0.f, 0.f};
      zL = MFMA_BF16(cl0, pa0, zL);
      zL = MFMA_BF16(cl1, pa1, zL);
      f32x4 zG = (f32x4){0.f, 0.f, 0.f, 0.f};
      zG = MFMA_BF16(cg0, pa0, zG);
      zG = MFMA_BF16(cg1, pa1, zG);
      const int t = mtT * 16 + l15;
      if (t < 40) {
        const size_t ctd = ((size_t)(c * 40 + t) << 10) + d0 + quad * 4;
        const f32x4 pl = *(const f32x4*)(preL + ctd);
        const f32x4 pg = *(const f32x4*)(preG + ctd);
        const f32x4 cf = *(const f32x4*)(capf + ctd);
        u16 ov[4];
#pragma unroll
        for (int rg = 0; rg < 4; ++rg) {
          const float aL = zL[rg] + pl[rg] + bl4[rg];
          const float aG = zG[rg] + pg[rg] + bg4[rg];
          const float g = frcp(1.f + __expf(-aG));
          const float u = 2.f * frcp(1.f + __expf(-2.f * aL)) - 1.f;  // tanh
          ov[rg] = f2bf(cf[rg] * g + u * (1.f - g));
        }
        *(uint2*)(lsQw + t * 32 + quad * 4) = *(const uint2*)ov;
      }
    }
    // S2 partial for this 16-d chunk (K padded to 32 with zeros in lsQ).
    // In-wave DS ordering guarantees the q2 writes above are visible.
    bf16x8 af2[3], bq2[3];
#pragma unroll
    for (int mt = 0; mt < 3; ++mt)
      af2[mt] = avalid[mt] ? *(const bf16x8*)(arow[mt] + d0 + quad * 8) : zero8;
#pragma unroll
    for (int nt = 0; nt < 3; ++nt)
      bq2[nt] = *(const bf16x8*)(lsQw + (nt * 16 + l15) * 32 + quad * 8);
#pragma unroll
    for (int mt = 0; mt < 3; ++mt)
#pragma unroll
      for (int nt = 0; nt < 3; ++nt)
        accS2[mt][nt] = MFMA_BF16(af2[mt], bq2[nt], accS2[mt][nt]);
  }
#pragma unroll
  for (int mt = 0; mt < 3; ++mt)
#pragma unroll
    for (int nt = 0; nt < 3; ++nt)
#pragma unroll
      for (int rg = 0; rg < 4; ++rg)
        atomicAdd(&lsS2[(nt * 16 + l15) * 52 + mt * 16 + quad * 4 + rg],
                  accS2[mt][nt][rg]);
  __syncthreads();

  if (wv == 0) softmax_w(lsS2, lsAT, quad, l15);
  __syncthreads();

  if (wv == 1) {
    const float sim2 = score_w(lsAT, lsS, Ghi, Glo, cnorm, c, i, quad, l15);
    if (lane == 0) score[i * 32 + c] = sim + sim2;
  }
}

// ---------------------------------------------------------------------------
extern "C" void kernel_launch(void* const* d_in, const int* in_sizes, int n_in,
                              void* d_out, int out_size, void* d_ws, size_t ws_size,
                              hipStream_t stream) {
  const float* img = (const float*)d_in[0];   // [32][36][1024] fp32
  const float* cap = (const float*)d_in[1];   // [32][40][1024] fp32
  const float* Wl  = (const float*)d_in[2];   // [2048][1024] fp32
  const float* bl  = (const float*)d_in[3];   // [1024] fp32
  const float* Wg  = (const float*)d_in[4];
  const float* bg  = (const float*)d_in[5];
  float* out = (float*)d_out;                 // [32][32] fp32

  char* ws = (char*)d_ws;
  float* cnrm = (float*)ws;               ws += 5120;
  u16*   WTl  = (u16*)ws;                 ws += (size_t)1024 * 2048 * 2;   // 4.2 MB
  u16*   WTg  = (u16*)ws;                 ws += (size_t)1024 * 2048 * 2;   // 4.2 MB
  float* preL = (float*)ws;               ws += (size_t)1280 * 1024 * 4;   // 5.2 MB
  float* preG = (float*)ws;               ws += (size_t)1280 * 1024 * 4;   // 5.2 MB
  u16*   imgb = (u16*)ws;                 ws += (size_t)1152 * 1024 * 2;   // 2.4 MB
  u16*   capb = (u16*)ws;                 ws += (size_t)1280 * 1024 * 2;   // 2.6 MB
  u16*   Ghi  = (u16*)ws;                 ws += (size_t)32 * 48 * 64 * 2;  // 196 KB
  u16*   Glo  = (u16*)ws;                 ws += (size_t)32 * 48 * 64 * 2;  // 196 KB
  u16*   cwTL = (u16*)ws;                 ws += (size_t)32 * 1024 * 40 * 2 + 256;
  u16*   cwTG = (u16*)ws;                 ws += (size_t)32 * 1024 * 40 * 2 + 256;
  float* cwL  = (float*)ws;               ws += (size_t)1152 * 1024 * 4;   // 4.7 MB
  float* cwG  = (float*)ws;               ws += (size_t)1152 * 1024 * 4;   // 4.7 MB

  cvt_k<<<1152, 256, 0, stream>>>(img, imgb);
  cvt_k<<<1280, 256, 0, stream>>>(cap, capb);
  transpose_k<<<dim3(64, 32, 2), dim3(32, 8), 0, stream>>>(Wl, Wg, WTl, WTg);
  capnorm_k<<<320, 256, 0, stream>>>(cap, cnrm);
  gram_k<<<32, 256, 0, stream>>>(imgb, Ghi, Glo);
  gemm_w<0><<<80, 256, 0, stream>>>(capb, WTl, WTg, preL, preG);   // cap@W_top
  gemm_w<1><<<72, 256, 0, stream>>>(imgb, WTl, WTg, cwL, cwG);     // img@W_bot
  cwt_k<<<128, 256, 0, stream>>>(cwL, cwTL);
  cwt_k<<<128, 256, 0, stream>>>(cwG, cwTG);
  attn_k<<<1024, 256, 0, stream>>>(imgb, capb, cwTL, cwTG, preL, preG,
                                   cap, bl, bg, cnrm, Ghi, Glo, out);
}

// Round 3
// 305.248 us; speedup vs baseline: 1.3259x; 1.3259x over previous
//
#include <hip/hip_runtime.h>
#include <stdint.h>

// C=32 captions, I=32 images, T=40 words, R=36 regions, D=1024.
// R14: GEMM-ification. R13's fused per-pair kernel was latency-bound
// (MfmaUtil 4.3%, VALUBusy 17%, nothing saturated). Restructure:
//   S1[i][ct][48] = ctx_i@cap^T        (s12gemm_k, batched 128x48xK1024)
//   score_k<0>: softmax->P1[i][ct][64] bf16 (GEMM operand layout) + sim1
//   gate_k: per-i GEMM q2[ct][d] = gate(P1@cw + pre), A=cwT B=P1 K=64,
//           128x128 tiles, XOR-swizzled LDS (stride-128B rows would be
//           16-way bank conflict), packed epilogue, q2 -> HBM (84MB, ~13us)
//   S2 = ctx_i@q2^T (same s12gemm_k), score_k<1> -> out.
// q2 HBM round-trip (~27us) is far cheaper than the serialized fusion.
// Overlays keep ws within the proven budget: P1->WT, S2->pre+capb, cw->q2.

typedef unsigned short u16;
typedef __attribute__((ext_vector_type(8))) short bf16x8;
typedef __attribute__((ext_vector_type(4))) float f32x4;

#define MFMA_BF16(a, b, c) __builtin_amdgcn_mfma_f32_16x16x32_bf16((a), (b), (c), 0, 0, 0)

__device__ __forceinline__ float bf2f(u16 u) {
  union { unsigned v; float f; } x; x.v = ((unsigned)u) << 16; return x.f;
}
__device__ __forceinline__ u16 f2bf(float f) {  // round-to-nearest-even
  union { float f; unsigned v; } x; x.f = f;
  return (u16)((x.v + 0x7fffu + ((x.v >> 16) & 1u)) >> 16);
}
__device__ __forceinline__ float frcp(float x) { return __builtin_amdgcn_rcpf(x); }
// async 16B global->LDS (DMA; LDS dest = wave-uniform base + lane*16)
__device__ __forceinline__ void gl2lds16(const u16* g, u16* l) {
  __builtin_amdgcn_global_load_lds((const __attribute__((address_space(1))) void*)g,
                                   (__attribute__((address_space(3))) void*)l, 16, 0, 0);
}

// ---------------------------------------------------------------------------
__global__ void cvt_k(const float* __restrict__ src, u16* __restrict__ dst) {
  const int idx = (blockIdx.x * 256 + threadIdx.x) * 4;
  const float4 v = *(const float4*)(src + idx);
  u16 o[4] = {f2bf(v.x), f2bf(v.y), f2bf(v.z), f2bf(v.w)};
  *(uint2*)(dst + idx) = *(const uint2*)o;
}

// Build cwT[i][d][64] bf16 from cw fp32 [i*36+r][1024]; r pad 36..63 = 0.
__global__ void cwt_k(const float* __restrict__ cw, u16* __restrict__ cwT) {
  const int g = blockIdx.x * 256 + threadIdx.x;  // i*1024+d
  const int i = g >> 10, d = g & 1023;
  u16 row[64];
#pragma unroll
  for (int r = 0; r < 36; ++r) row[r] = f2bf(cw[((size_t)(i * 36 + r) << 10) + d]);
#pragma unroll
  for (int r = 36; r < 64; ++r) row[r] = 0;
  u16* dst = cwT + (size_t)g * 64;
#pragma unroll
  for (int j = 0; j < 8; ++j) *(uint4*)(dst + j * 8) = *(const uint4*)(row + j * 8);
}

// ---------------------------------------------------------------------------
__global__ void capnorm_k(const float* __restrict__ cap, float* __restrict__ cnorm) {
  const int wv = threadIdx.x >> 6, lane = threadIdx.x & 63;
  const int row = blockIdx.x * 4 + wv;  // < 1280
  const float* p = cap + ((size_t)row << 10) + lane * 16;
  float s = 0.f;
#pragma unroll
  for (int e = 0; e < 16; ++e) { float v = p[e]; s += v * v; }
#pragma unroll
  for (int off = 32; off > 0; off >>= 1) s += __shfl_down(s, off, 64);
  if (lane == 0) cnorm[row] = sqrtf(s);
}

// ---------------------------------------------------------------------------
__global__ void transpose_k(const float* __restrict__ Wl, const float* __restrict__ Wg,
                            u16* __restrict__ WTl, u16* __restrict__ WTg) {
  __shared__ u16 tile[32][33];
  const float* src = blockIdx.z ? Wg : Wl;
  u16* dst = blockIdx.z ? WTg : WTl;
  const int k0 = blockIdx.x * 32, n0 = blockIdx.y * 32;
  const int tx = threadIdx.x, ty = threadIdx.y;
#pragma unroll
  for (int j = 0; j < 4; ++j)
    tile[ty + 8 * j][tx] = f2bf(src[(size_t)(k0 + ty + 8 * j) * 1024 + n0 + tx]);
  __syncthreads();
#pragma unroll
  for (int j = 0; j < 4; ++j)
    dst[(size_t)(n0 + ty + 8 * j) * 2048 + k0 + tx] = tile[tx][ty + 8 * j];
}

// ---------------------------------------------------------------------------
// Dual-B GEMM: out{L,G}[m,n] = sum_k A[m,k]*W{l,g}[kofs+k][n], K=1024.
// IMGW=0: bf16 out with bias folded (pre' = cap@W + b). IMGW=1: fp32 out.
template <int IMGW>
__global__ __launch_bounds__(256, 2) void gemm_w(
    const u16* __restrict__ A, const u16* __restrict__ WTl, const u16* __restrict__ WTg,
    void* __restrict__ outL_, void* __restrict__ outG_,
    const float* __restrict__ bL, const float* __restrict__ bG) {
  __shared__ __align__(16) u16 lsA[128 * 32];
  __shared__ __align__(16) u16 lsBl[128 * 32];
  __shared__ __align__(16) u16 lsBg[128 * 32];
  const int tid = threadIdx.x;
  const int bm = blockIdx.x >> 3, bn = blockIdx.x & 7;
  const int wv = tid >> 6, lane = tid & 63;
  const int quad = lane >> 4, l15 = lane & 15;
  const int wm = (wv & 1) << 6, wn = (wv >> 1) << 6;
  const int kofs = IMGW ? 1024 : 0;

  f32x4 accL[4][4], accG[4][4];
#pragma unroll
  for (int a = 0; a < 4; ++a)
#pragma unroll
    for (int b = 0; b < 4; ++b) {
      accL[a][b] = (f32x4){0.f, 0.f, 0.f, 0.f};
      accG[a][b] = (f32x4){0.f, 0.f, 0.f, 0.f};
    }

  const size_t arow0 = (size_t)bm * 128 * 1024;
  for (int kt = 0; kt < 32; ++kt) {
    if (kt) __syncthreads();
#pragma unroll
    for (int s = 0; s < 2; ++s) {
      const int idx = s * 256 + tid;
      const int row = idx >> 2, c8 = idx & 3;
      gl2lds16(A + arow0 + (size_t)row * 1024 + kt * 32 + c8 * 8,
               lsA + (size_t)(s * 256 + wv * 64) * 8);
      const size_t bro = (size_t)(bn * 128 + row) * 2048 + kofs + kt * 32 + c8 * 8;
      gl2lds16(WTl + bro, lsBl + (size_t)(s * 256 + wv * 64) * 8);
      gl2lds16(WTg + bro, lsBg + (size_t)(s * 256 + wv * 64) * 8);
    }
    __syncthreads();
    bf16x8 af[4], bl8[4], bg8[4];
#pragma unroll
    for (int mt = 0; mt < 4; ++mt)
      af[mt] = *(const bf16x8*)(lsA + (wm + mt * 16 + l15) * 32 + quad * 8);
#pragma unroll
    for (int nt = 0; nt < 4; ++nt) {
      bl8[nt] = *(const bf16x8*)(lsBl + (wn + nt * 16 + l15) * 32 + quad * 8);
      bg8[nt] = *(const bf16x8*)(lsBg + (wn + nt * 16 + l15) * 32 + quad * 8);
    }
#pragma unroll
    for (int mt = 0; mt < 4; ++mt)
#pragma unroll
      for (int nt = 0; nt < 4; ++nt) {
        accL[mt][nt] = MFMA_BF16(af[mt], bl8[nt], accL[mt][nt]);
        accG[mt][nt] = MFMA_BF16(af[mt], bg8[nt], accG[mt][nt]);
      }
  }
#pragma unroll
  for (int mt = 0; mt < 4; ++mt)
#pragma unroll
    for (int nt = 0; nt < 4; ++nt) {
      const int n = bn * 128 + wn + nt * 16 + l15;
      float blv = 0.f, bgv = 0.f;
      if (!IMGW) { blv = bL[n]; bgv = bG[n]; }
#pragma unroll
      for (int r = 0; r < 4; ++r) {
        const int m = bm * 128 + wm + mt * 16 + quad * 4 + r;
        if (IMGW) {
          ((float*)outL_)[(size_t)m * 1024 + n] = accL[mt][nt][r];
          ((float*)outG_)[(size_t)m * 1024 + n] = accG[mt][nt][r];
        } else {
          ((u16*)outL_)[(size_t)m * 1024 + n] = f2bf(accL[mt][nt][r] + blv);
          ((u16*)outG_)[(size_t)m * 1024 + n] = f2bf(accG[mt][nt][r] + bgv);
        }
      }
    }
}

// ---------------------------------------------------------------------------
// Per-image Gram: G[i] = ctx_i @ ctx_i^T [36x36], stored [48][64] bf16 hi+lo.
__global__ __launch_bounds__(256, 2) void gram_k(const u16* __restrict__ imgb,
                                                 u16* __restrict__ Ghi,
                                                 u16* __restrict__ Glo) {
  __shared__ float lsS[48 * 52];
  const int tid = threadIdx.x;
  const int i = blockIdx.x;
  const int wv = tid >> 6, lane = tid & 63;
  const int quad = lane >> 4, l15 = lane & 15;
  for (int k = tid; k < 48 * 52; k += 256) lsS[k] = 0.f;

  const u16* arow[3]; bool avalid[3];
#pragma unroll
  for (int mt = 0; mt < 3; ++mt) {
    const int r = mt * 16 + l15;
    avalid[mt] = r < 36;
    arow[mt] = imgb + ((size_t)(i * 36 + (r < 36 ? r : 35)) << 10);
  }
  const bf16x8 zero8 = {0, 0, 0, 0, 0, 0, 0, 0};
  f32x4 acc[3][3];
#pragma unroll
  for (int a = 0; a < 3; ++a)
#pragma unroll
    for (int b = 0; b < 3; ++b) acc[a][b] = (f32x4){0.f, 0.f, 0.f, 0.f};

  for (int kk = wv * 8; kk < wv * 8 + 8; ++kk) {
    const int ko = kk * 32 + quad * 8;
    bf16x8 af[3];
#pragma unroll
    for (int mt = 0; mt < 3; ++mt)
      af[mt] = avalid[mt] ? *(const bf16x8*)(arow[mt] + ko) : zero8;
#pragma unroll
    for (int mt = 0; mt < 3; ++mt)
#pragma unroll
      for (int nt = 0; nt < 3; ++nt)
        acc[mt][nt] = MFMA_BF16(af[mt], af[nt], acc[mt][nt]);
  }
  __syncthreads();
#pragma unroll
  for (int mt = 0; mt < 3; ++mt)
#pragma unroll
    for (int nt = 0; nt < 3; ++nt)
#pragma unroll
      for (int rg = 0; rg < 4; ++rg)
        atomicAdd(&lsS[(nt * 16 + l15) * 52 + mt * 16 + quad * 4 + rg],
                  acc[mt][nt][rg]);
  __syncthreads();
  if (wv == 0) {
#pragma unroll
    for (int nt = 0; nt < 3; ++nt) {
      const int rp = nt * 16 + l15;  // stored row (G symmetric)
#pragma unroll
      for (int mt = 0; mt < 3; ++mt) {
        const f32x4 g = *(const f32x4*)&lsS[rp * 52 + mt * 16 + quad * 4];
        u16 hv[4], lv[4];
#pragma unroll
        for (int rg = 0; rg < 4; ++rg) {
          hv[rg] = f2bf(g[rg]);
          lv[rg] = f2bf(g[rg] - bf2f(hv[rg]));
        }
        const size_t gb = ((size_t)i * 48 + rp) * 64 + mt * 16 + quad * 4;
        *(uint2*)(Ghi + gb) = *(const uint2*)hv;
        *(uint2*)(Glo + gb) = *(const uint2*)lv;
      }
    }
  }
  for (int k = tid; k < 48 * 16; k += 256) {  // zero cols 48..63
    const size_t gb = ((size_t)i * 48 + (k >> 4)) * 64 + 48 + (k & 15);
    Ghi[gb] = 0; Glo[gb] = 0;
  }
}

// ---------------------------------------------------------------------------
// Batched small-N GEMM: out[i][m][r] = sum_d A[m,d]*ctx_i[r,d], m-tile 128,
// N=48 (r>=36 zero via frag masking), K=1024. A = capb (shared) or q2_i.
__global__ __launch_bounds__(256, 4) void s12gemm_k(
    const u16* __restrict__ Abase, const int perI,
    const u16* __restrict__ imgb, float* __restrict__ out) {
  __shared__ __align__(16) u16 lsA[128 * 32];
  __shared__ __align__(16) u16 lsB[64 * 32];
  const int tid = threadIdx.x;
  const int m0 = blockIdx.x * 128;
  const int i = blockIdx.y;
  const int wv = tid >> 6, lane = tid & 63;
  const int quad = lane >> 4, l15 = lane & 15;
  const u16* A = Abase + (perI ? ((size_t)i * 1280 * 1024) : 0);
  const u16* B = imgb + (size_t)i * 36 * 1024;
  const bf16x8 zero8 = {0, 0, 0, 0, 0, 0, 0, 0};

  f32x4 acc[2][3];
#pragma unroll
  for (int a = 0; a < 2; ++a)
#pragma unroll
    for (int b = 0; b < 3; ++b) acc[a][b] = (f32x4){0.f, 0.f, 0.f, 0.f};

  for (int kt = 0; kt < 32; ++kt) {
    if (kt) __syncthreads();
#pragma unroll
    for (int s = 0; s < 2; ++s) {  // A: 512 chunks of 16B
      const int idx = s * 256 + tid;
      const int rr = idx >> 2, j = idx & 3;
      const int js = j ^ ((rr >> 2) & 3);  // bank swizzle
      gl2lds16(A + (size_t)(m0 + rr) * 1024 + kt * 32 + js * 8,
               lsA + (size_t)(s * 256 + wv * 64) * 8);
    }
    {  // B: 256 chunks (64 rows; rows >=36 clamped, masked at frag level)
      const int rr = tid >> 2, j = tid & 3;
      const int rc = rr < 36 ? rr : 35;
      const int js = j ^ ((rr >> 2) & 3);
      gl2lds16(B + (size_t)rc * 1024 + kt * 32 + js * 8,
               lsB + (size_t)(wv * 64) * 8);
    }
    __syncthreads();
    bf16x8 a2[2], b3[3];
#pragma unroll
    for (int mf = 0; mf < 2; ++mf) {
      const int ra = wv * 32 + mf * 16 + l15;
      a2[mf] = *(const bf16x8*)(lsA + ra * 32 + (quad ^ ((ra >> 2) & 3)) * 8);
    }
#pragma unroll
    for (int nf = 0; nf < 3; ++nf) {
      const int rb = nf * 16 + l15;
      const bf16x8 bv = *(const bf16x8*)(lsB + rb * 32 + (quad ^ ((rb >> 2) & 3)) * 8);
      b3[nf] = (rb < 36) ? bv : zero8;
    }
#pragma unroll
    for (int mf = 0; mf < 2; ++mf)
#pragma unroll
      for (int nf = 0; nf < 3; ++nf)
        acc[mf][nf] = MFMA_BF16(a2[mf], b3[nf], acc[mf][nf]);
  }
#pragma unroll
  for (int mf = 0; mf < 2; ++mf)
#pragma unroll
    for (int nf = 0; nf < 3; ++nf)
#pragma unroll
      for (int rg = 0; rg < 4; ++rg) {
        const int m = m0 + wv * 32 + mf * 16 + quad * 4 + rg;
        out[((size_t)i * 1280 + m) * 48 + nf * 16 + l15] = acc[mf][nf][rg];
      }
}

// ---------------------------------------------------------------------------
// Per-i gating GEMM: q2[i][ct][d] = gate(sum_r cwT_i[d][r]*P1_i[ct][r] + pre).
// A = cwT (rows d), B = P1 (rows ct), K = 64 (r pad). XOR-swizzled LDS.
__global__ __launch_bounds__(256, 2) void gate_k(
    const u16* __restrict__ cwTL, const u16* __restrict__ cwTG,
    const u16* __restrict__ P1, const u16* __restrict__ preL,
    const u16* __restrict__ preG, const float* __restrict__ capf,
    u16* __restrict__ q2) {
  __shared__ __align__(16) u16 lsCl[128 * 64];
  __shared__ __align__(16) u16 lsCg[128 * 64];
  __shared__ __align__(16) u16 lsP[128 * 64];
  const int tid = threadIdx.x;
  const int bd = blockIdx.x & 7, bct = blockIdx.x >> 3;  // 8 d-tiles x 10 ct-tiles
  const int i = blockIdx.y;
  const int d0 = bd * 128, ct0 = bct * 128;
  const int wv = tid >> 6, lane = tid & 63;
  const int quad = lane >> 4, l15 = lane & 15;

#pragma unroll
  for (int s = 0; s < 4; ++s) {  // 1024 chunks per tile
    const int idx = s * 256 + tid;
    const int rr = idx >> 3, j = idx & 7;
    const int js = j ^ (rr & 7);  // inverse-swizzled source, linear dest
    const size_t dofs = (size_t)(s * 256 + wv * 64) * 8;
    gl2lds16(cwTL + ((size_t)(i << 10) + d0 + rr) * 64 + js * 8, lsCl + dofs);
    gl2lds16(cwTG + ((size_t)(i << 10) + d0 + rr) * 64 + js * 8, lsCg + dofs);
    gl2lds16(P1 + ((size_t)i * 1280 + ct0 + rr) * 64 + js * 8, lsP + dofs);
  }
  __syncthreads();

  const int wm = (wv & 1) * 64, wn = (wv >> 1) * 64;
  f32x4 accL[4][4], accG[4][4];
#pragma unroll
  for (int a = 0; a < 4; ++a)
#pragma unroll
    for (int b = 0; b < 4; ++b) {
      accL[a][b] = (f32x4){0.f, 0.f, 0.f, 0.f};
      accG[a][b] = (f32x4){0.f, 0.f, 0.f, 0.f};
    }
#pragma unroll
  for (int ks = 0; ks < 2; ++ks) {
    bf16x8 al[4], ag[4], bp[4];
#pragma unroll
    for (int mt = 0; mt < 4; ++mt) {
      const int ra = wm + mt * 16 + l15;
      const int off = ra * 64 + (((ks * 4 + quad) ^ (ra & 7)) * 8);
      al[mt] = *(const bf16x8*)(lsCl + off);
      ag[mt] = *(const bf16x8*)(lsCg + off);
    }
#pragma unroll
    for (int nt = 0; nt < 4; ++nt) {
      const int rb = wn + nt * 16 + l15;
      bp[nt] = *(const bf16x8*)(lsP + rb * 64 + (((ks * 4 + quad) ^ (rb & 7)) * 8));
    }
#pragma unroll
    for (int mt = 0; mt < 4; ++mt)
#pragma unroll
      for (int nt = 0; nt < 4; ++nt) {
        accL[mt][nt] = MFMA_BF16(al[mt], bp[nt], accL[mt][nt]);
        accG[mt][nt] = MFMA_BF16(ag[mt], bp[nt], accG[mt][nt]);
      }
  }
  // Epilogue: lane holds 4 consecutive d (rows) for one ct (col).
#pragma unroll
  for (int mt = 0; mt < 4; ++mt) {
    const int D0 = d0 + wm + mt * 16 + quad * 4;
#pragma unroll
    for (int nt = 0; nt < 4; ++nt) {
      const int ct = ct0 + wn + nt * 16 + l15;
      const size_t rb = (size_t)ct << 10;
      const uint2 plv = *(const uint2*)(preL + rb + D0);
      const uint2 pgv = *(const uint2*)(preG + rb + D0);
      const f32x4 cf = *(const f32x4*)(capf + rb + D0);
      const float pl4[4] = {bf2f((u16)(plv.x & 0xffffu)), bf2f((u16)(plv.x >> 16)),
                            bf2f((u16)(plv.y & 0xffffu)), bf2f((u16)(plv.y >> 16))};
      const float pg4[4] = {bf2f((u16)(pgv.x & 0xffffu)), bf2f((u16)(pgv.x >> 16)),
                            bf2f((u16)(pgv.y & 0xffffu)), bf2f((u16)(pgv.y >> 16))};
      u16 ov[4];
#pragma unroll
      for (int rg = 0; rg < 4; ++rg) {
        const float aL = accL[mt][nt][rg] + pl4[rg];
        const float aG = accG[mt][nt][rg] + pg4[rg];
        const float g = frcp(1.f + __expf(-aG));
        const float u = 2.f * frcp(1.f + __expf(-2.f * aL)) - 1.f;  // tanh
        ov[rg] = f2bf(cf[rg] * g + u * (1.f - g));
      }
      *(uint2*)(q2 + (((size_t)i * 1280 + ct) << 10) + D0) = *(const uint2*)ov;
    }
  }
}

// ---------------------------------------------------------------------------
// Per-pair scoring (4 pairs/block, one per wave). Softmax(Ssm) -> P;
// pn = sum P*S1; pw = P^T G P; sim = mean cosine. PASS2=0 also writes P1+sim1;
// PASS2=1 writes score = sim1 + sim2.
template <int PASS2>
__global__ __launch_bounds__(256, 2) void score_k(
    const float* __restrict__ Ssm, const float* __restrict__ S1,
    const u16* __restrict__ Ghi, const u16* __restrict__ Glo,
    const float* __restrict__ cnorm, u16* __restrict__ P1,
    float* __restrict__ sim1, float* __restrict__ score) {
  __shared__ __align__(16) u16 lsP[4][48 * 72];
  const int tid = threadIdx.x;
  const int wv = tid >> 6, lane = tid & 63;
  const int quad = lane >> 4, l15 = lane & 15;
  const int pair = blockIdx.x * 4 + wv;
  const int c = pair >> 5, i = pair & 31;
  u16* lsPw = lsP[wv];
  for (int k = lane; k < 1728; k += 64) ((unsigned*)lsPw)[k] = 0u;

  float sS[3][3][4], s1f[3][3][4];
  const float* Sb = Ssm + ((size_t)i * 1280 + c * 40) * 48;
  const float* S1b = S1 + ((size_t)i * 1280 + c * 40) * 48;
#pragma unroll
  for (int nt = 0; nt < 3; ++nt) {
    const int t = nt * 16 + l15;
    const int tr = t < 40 ? t : 39;
#pragma unroll
    for (int mt = 0; mt < 3; ++mt) {
      f32x4 v = *(const f32x4*)(Sb + (size_t)tr * 48 + mt * 16 + quad * 4);
      if (t >= 40) v = (f32x4){0.f, 0.f, 0.f, 0.f};  // keep l2norm-over-t exact
#pragma unroll
      for (int rg = 0; rg < 4; ++rg) sS[mt][nt][rg] = v[rg];
      if (PASS2) {
        const f32x4 w = *(const f32x4*)(S1b + (size_t)tr * 48 + mt * 16 + quad * 4);
#pragma unroll
        for (int rg = 0; rg < 4; ++rg) s1f[mt][nt][rg] = w[rg];
      } else {
#pragma unroll
        for (int rg = 0; rg < 4; ++rg) s1f[mt][nt][rg] = v[rg];
      }
    }
  }

  // ---- leaky + l2norm over t, temperature softmax over r (in-register)
  float rn[3][4];
#pragma unroll
  for (int mt = 0; mt < 3; ++mt)
#pragma unroll
    for (int rg = 0; rg < 4; ++rg) {
      float s2 = 0.f;
#pragma unroll
      for (int nt = 0; nt < 3; ++nt) {
        float v = sS[mt][nt][rg]; v = v > 0.f ? v : 0.1f * v; s2 += v * v;
      }
      s2 += __shfl_xor(s2, 1, 64); s2 += __shfl_xor(s2, 2, 64);
      s2 += __shfl_xor(s2, 4, 64); s2 += __shfl_xor(s2, 8, 64);
      rn[mt][rg] = sqrtf(s2) + 1e-8f;
    }
  float mx[3] = {-3.0e38f, -3.0e38f, -3.0e38f};
#pragma unroll
  for (int mt = 0; mt < 3; ++mt)
#pragma unroll
    for (int nt = 0; nt < 3; ++nt)
#pragma unroll
      for (int rg = 0; rg < 4; ++rg) {
        const int r = mt * 16 + quad * 4 + rg;
        float v = sS[mt][nt][rg]; v = v > 0.f ? v : 0.1f * v;
        float zz = 9.f * v / rn[mt][rg];
        zz = (r < 36) ? zz : -3.0e38f;
        sS[mt][nt][rg] = zz;
        mx[nt] = fmaxf(mx[nt], zz);
      }
#pragma unroll
  for (int nt = 0; nt < 3; ++nt) {
    mx[nt] = fmaxf(mx[nt], __shfl_xor(mx[nt], 16, 64));
    mx[nt] = fmaxf(mx[nt], __shfl_xor(mx[nt], 32, 64));
  }
  float ss[3] = {0.f, 0.f, 0.f};
#pragma unroll
  for (int mt = 0; mt < 3; ++mt)
#pragma unroll
    for (int nt = 0; nt < 3; ++nt)
#pragma unroll
      for (int rg = 0; rg < 4; ++rg) {
        const float e = __expf(sS[mt][nt][rg] - mx[nt]);
        sS[mt][nt][rg] = e; ss[nt] += e;
      }
#pragma unroll
  for (int nt = 0; nt < 3; ++nt) {
    ss[nt] += __shfl_xor(ss[nt], 16, 64);
    ss[nt] += __shfl_xor(ss[nt], 32, 64);
    ss[nt] = 1.f / ss[nt];
  }
#pragma unroll
  for (int nt = 0; nt < 3; ++nt) {
    const int t = nt * 16 + l15;
#pragma unroll
    for (int mt = 0; mt < 3; ++mt) {
#pragma unroll
      for (int rg = 0; rg < 4; ++rg) sS[mt][nt][rg] *= ss[nt];
      if (t < 40) {
        u16 pv[4];
#pragma unroll
        for (int rg = 0; rg < 4; ++rg) pv[rg] = f2bf(sS[mt][nt][rg]);
        *(uint2*)(lsPw + t * 72 + mt * 16 + quad * 4) = *(const uint2*)pv;
      }
    }
  }

  // ---- pn = sum_r P * S1raw (per t)
  float pnv[3] = {0.f, 0.f, 0.f};
#pragma unroll
  for (int nt = 0; nt < 3; ++nt)
#pragma unroll
    for (int mt = 0; mt < 3; ++mt)
#pragma unroll
      for (int rg = 0; rg < 4; ++rg) pnv[nt] += sS[mt][nt][rg] * s1f[mt][nt][rg];

  // ---- P1 global write (GEMM operand layout, stride 64, zeros beyond r=48)
  if (!PASS2) {
    for (int idx = lane; idx < 320; idx += 64) {
      const int t = idx >> 3, j = idx & 7;
      *(uint4*)(P1 + ((size_t)i * 1280 + c * 40 + t) * 64 + j * 8) =
          *(const uint4*)(lsPw + t * 72 + j * 8);
    }
  }

  // ---- pw = P^T G P via Gram MFMA
  bf16x8 afA[3][2];
#pragma unroll
  for (int mtT = 0; mtT < 3; ++mtT)
#pragma unroll
    for (int ks = 0; ks < 2; ++ks)
      afA[mtT][ks] =
          *(const bf16x8*)(lsPw + (mtT * 16 + l15) * 72 + ks * 32 + quad * 8);
  f32x4 gp[3][3];
#pragma unroll
  for (int a = 0; a < 3; ++a)
#pragma unroll
    for (int b = 0; b < 3; ++b) gp[a][b] = (f32x4){0.f, 0.f, 0.f, 0.f};
#pragma unroll
  for (int ks = 0; ks < 2; ++ks)
#pragma unroll
    for (int mtG = 0; mtG < 3; ++mtG) {
      const size_t gb = ((size_t)i * 48 + mtG * 16 + l15) * 64 + ks * 32 + quad * 8;
      const bf16x8 gh = *(const bf16x8*)(Ghi + gb);
      const bf16x8 gl = *(const bf16x8*)(Glo + gb);
#pragma unroll
      for (int mtT = 0; mtT < 3; ++mtT) {
        gp[mtG][mtT] = MFMA_BF16(gh, afA[mtT][ks], gp[mtG][mtT]);
        gp[mtG][mtT] = MFMA_BF16(gl, afA[mtT][ks], gp[mtG][mtT]);
      }
    }
  float pwv[3] = {0.f, 0.f, 0.f};
#pragma unroll
  for (int nt = 0; nt < 3; ++nt)
#pragma unroll
    for (int mt = 0; mt < 3; ++mt)
#pragma unroll
      for (int rg = 0; rg < 4; ++rg)
        pwv[nt] += sS[mt][nt][rg] * gp[mt][nt][rg];
#pragma unroll
  for (int nt = 0; nt < 3; ++nt) {
    pnv[nt] += __shfl_xor(pnv[nt], 16, 64); pnv[nt] += __shfl_xor(pnv[nt], 32, 64);
    pwv[nt] += __shfl_xor(pwv[nt], 16, 64); pwv[nt] += __shfl_xor(pwv[nt], 32, 64);
  }
  float tot = 0.f;
#pragma unroll
  for (int nt = 0; nt < 3; ++nt) {
    const int t = nt * 16 + l15;
    if (t < 40) {
      const float w2 = sqrtf(fmaxf(pwv[nt], 0.f));
      tot += pnv[nt] / fmaxf(cnorm[c * 40 + t] * w2, 1e-8f);
    }
  }
  tot += __shfl_xor(tot, 1, 64); tot += __shfl_xor(tot, 2, 64);
  tot += __shfl_xor(tot, 4, 64); tot += __shfl_xor(tot, 8, 64);
  if (lane == 0) {
    const float s = tot * (1.f / 40.f);
    if (PASS2) score[i * 32 + c] = sim1[pair] + s;
    else sim1[pair] = s;
  }
}

// ---------------------------------------------------------------------------
extern "C" void kernel_launch(void* const* d_in, const int* in_sizes, int n_in,
                              void* d_out, int out_size, void* d_ws, size_t ws_size,
                              hipStream_t stream) {
  const float* img = (const float*)d_in[0];   // [32][36][1024] fp32
  const float* cap = (const float*)d_in[1];   // [32][40][1024] fp32
  const float* Wl  = (const float*)d_in[2];   // [2048][1024] fp32
  const float* bl  = (const float*)d_in[3];   // [1024] fp32
  const float* Wg  = (const float*)d_in[4];
  const float* bg  = (const float*)d_in[5];
  float* out = (float*)d_out;                 // [32][32] fp32

  char* ws = (char*)d_ws;
  float* cnrm = (float*)ws;               ws += 5120;
  float* sim1 = (float*)ws;               ws += 4096;
  u16*   WTl  = (u16*)ws;                 ws += (size_t)1024 * 2048 * 2;   // 4.2 MB
  u16*   WTg  = (u16*)ws;                 ws += (size_t)1024 * 2048 * 2;   // 4.2 MB
  u16*   preL = (u16*)ws;                 ws += (size_t)1280 * 1024 * 2;   // 2.6 MB
  u16*   preG = (u16*)ws;                 ws += (size_t)1280 * 1024 * 2;   // 2.6 MB
  u16*   capb = (u16*)ws;                 ws += (size_t)1280 * 1024 * 2;   // 2.6 MB
  u16*   imgb = (u16*)ws;                 ws += (size_t)1152 * 1024 * 2;   // 2.4 MB
  u16*   Ghi  = (u16*)ws;                 ws += (size_t)32 * 48 * 64 * 2;  // 196 KB
  u16*   Glo  = (u16*)ws;                 ws += (size_t)32 * 48 * 64 * 2;  // 196 KB
  u16*   cwTL = (u16*)ws;                 ws += (size_t)32 * 1024 * 64 * 2;  // 4.2 MB
  u16*   cwTG = (u16*)ws;                 ws += (size_t)32 * 1024 * 64 * 2;  // 4.2 MB
  float* S1   = (float*)ws;               ws += (size_t)32 * 1280 * 48 * 4;  // 7.9 MB
  u16*   q2   = (u16*)ws;                 ws += (size_t)32 * 1280 * 1024 * 2; // 83.9 MB
  // Overlays (lifetime-disjoint):
  u16*   P1   = WTl;                      // 5.2 MB <= WT region (dead after gemm_w)
  float* S2   = (float*)preL;             // 7.86 MB == pre+capb (dead after gate/s1gemm)
  float* cwL  = (float*)q2;               // 4.7 MB (dead after cwt_k, before q2 write)
  float* cwG  = cwL + (size_t)1152 * 1024;

  cvt_k<<<1152, 256, 0, stream>>>(img, imgb);
  cvt_k<<<1280, 256, 0, stream>>>(cap, capb);
  transpose_k<<<dim3(64, 32, 2), dim3(32, 8), 0, stream>>>(Wl, Wg, WTl, WTg);
  capnorm_k<<<320, 256, 0, stream>>>(cap, cnrm);
  gram_k<<<32, 256, 0, stream>>>(imgb, Ghi, Glo);
  gemm_w<0><<<80, 256, 0, stream>>>(capb, WTl, WTg, preL, preG, bl, bg);  // pre=cap@W+b
  gemm_w<1><<<72, 256, 0, stream>>>(imgb, WTl, WTg, cwL, cwG, nullptr, nullptr);
  cwt_k<<<128, 256, 0, stream>>>(cwL, cwTL);
  cwt_k<<<128, 256, 0, stream>>>(cwG, cwTG);
  s12gemm_k<<<dim3(10, 32), 256, 0, stream>>>(capb, 0, imgb, S1);
  score_k<0><<<256, 256, 0, stream>>>(S1, S1, Ghi, Glo, cnrm, P1, sim1, out);
  gate_k<<<dim3(80, 32), 256, 0, stream>>>(cwTL, cwTG, P1, preL, preG, cap, q2);
  s12gemm_k<<<dim3(10, 32), 256, 0, stream>>>(q2, 1, imgb, S2);
  score_k<1><<<256, 256, 0, stream>>>(S2, S1, Ghi, Glo, cnrm, P1, sim1, out);
}

// Round 4
// 292.612 us; speedup vs baseline: 1.3832x; 1.0432x over previous
//
#include <hip/hip_runtime.h>
#include <stdint.h>

// C=32 captions, I=32 images, T=40 words, R=36 regions, D=1024.
// R15: kill the q2 HBM round-trip + merge the small GEMMs.
//   gates2_k = gate_k + s12gemm<q2> fused: per (64-ct tile, i) block, loop
//     8 d-chunks of 128: stage cwT chunk (XOR-swz LDS) -> gate GEMM ->
//     gating epilogue writes q2 chunk to padded LDS [64ct][136] ->
//     S2 += ctx@q2chunk^T MFMA. q2 never hits HBM (-168MB traffic).
//     Grid 640, i fastest => image i pinned to XCD i%8 (cwT L2-hot).
//   gemmw_k = gemm_w<0> + gemm_w<1> merged (304 blocks, 64x128 tiles);
//     img part writes cwT[i][d][64] bf16 DIRECTLY (scatter, L2-merged),
//     deleting cwt_k x2 and the fp32 cw round-trip. cwT zero-padded by
//     zero_k (P1 is exact-zero at r>=36, but garbage NaN x 0 = NaN).
//   S1/score_k/s12gemm<cap> unchanged from R14 (passed).

typedef unsigned short u16;
typedef __attribute__((ext_vector_type(8))) short bf16x8;
typedef __attribute__((ext_vector_type(4))) float f32x4;

#define MFMA_BF16(a, b, c) __builtin_amdgcn_mfma_f32_16x16x32_bf16((a), (b), (c), 0, 0, 0)

__device__ __forceinline__ float bf2f(u16 u) {
  union { unsigned v; float f; } x; x.v = ((unsigned)u) << 16; return x.f;
}
__device__ __forceinline__ u16 f2bf(float f) {  // round-to-nearest-even
  union { float f; unsigned v; } x; x.f = f;
  return (u16)((x.v + 0x7fffu + ((x.v >> 16) & 1u)) >> 16);
}
__device__ __forceinline__ float frcp(float x) { return __builtin_amdgcn_rcpf(x); }
// async 16B global->LDS (DMA; LDS dest = wave-uniform base + lane*16)
__device__ __forceinline__ void gl2lds16(const u16* g, u16* l) {
  __builtin_amdgcn_global_load_lds((const __attribute__((address_space(1))) void*)g,
                                   (__attribute__((address_space(3))) void*)l, 16, 0, 0);
}

// ---------------------------------------------------------------------------
__global__ void cvt_k(const float* __restrict__ src, u16* __restrict__ dst) {
  const int idx = (blockIdx.x * 256 + threadIdx.x) * 4;
  const float4 v = *(const float4*)(src + idx);
  u16 o[4] = {f2bf(v.x), f2bf(v.y), f2bf(v.z), f2bf(v.w)};
  *(uint2*)(dst + idx) = *(const uint2*)o;
}

__global__ void zero_k(u16* __restrict__ p) {
  const int idx = (blockIdx.x * 256 + threadIdx.x) * 8;
  uint4 z; z.x = z.y = z.z = z.w = 0u;
  *(uint4*)(p + idx) = z;
}

// ---------------------------------------------------------------------------
__global__ void capnorm_k(const float* __restrict__ cap, float* __restrict__ cnorm) {
  const int wv = threadIdx.x >> 6, lane = threadIdx.x & 63;
  const int row = blockIdx.x * 4 + wv;  // < 1280
  const float* p = cap + ((size_t)row << 10) + lane * 16;
  float s = 0.f;
#pragma unroll
  for (int e = 0; e < 16; ++e) { float v = p[e]; s += v * v; }
#pragma unroll
  for (int off = 32; off > 0; off >>= 1) s += __shfl_down(s, off, 64);
  if (lane == 0) cnorm[row] = sqrtf(s);
}

// ---------------------------------------------------------------------------
__global__ void transpose_k(const float* __restrict__ Wl, const float* __restrict__ Wg,
                            u16* __restrict__ WTl, u16* __restrict__ WTg) {
  __shared__ u16 tile[32][33];
  const float* src = blockIdx.z ? Wg : Wl;
  u16* dst = blockIdx.z ? WTg : WTl;
  const int k0 = blockIdx.x * 32, n0 = blockIdx.y * 32;
  const int tx = threadIdx.x, ty = threadIdx.y;
#pragma unroll
  for (int j = 0; j < 4; ++j)
    tile[ty + 8 * j][tx] = f2bf(src[(size_t)(k0 + ty + 8 * j) * 1024 + n0 + tx]);
  __syncthreads();
#pragma unroll
  for (int j = 0; j < 4; ++j)
    dst[(size_t)(n0 + ty + 8 * j) * 2048 + k0 + tx] = tile[tx][ty + 8 * j];
}

// ---------------------------------------------------------------------------
// Merged dual-B GEMM over A = [capb(1280); imgb(1152)] rows, K=1024.
// bm<20: pre{L,G}[m][n] = cap@W_top + b (bf16). bm>=20: cwT{L,G}[i][d][64]
// direct-write (bf16 scatter; pad rows 36..63 pre-zeroed by zero_k).
__global__ __launch_bounds__(256, 2) void gemmw_k(
    const u16* __restrict__ capb, const u16* __restrict__ imgb,
    const u16* __restrict__ WTl, const u16* __restrict__ WTg,
    u16* __restrict__ preL, u16* __restrict__ preG,
    u16* __restrict__ cwTL, u16* __restrict__ cwTG,
    const float* __restrict__ bL, const float* __restrict__ bG) {
  __shared__ __align__(16) u16 lsA[64 * 32];
  __shared__ __align__(16) u16 lsBl[128 * 32];
  __shared__ __align__(16) u16 lsBg[128 * 32];
  const int tid = threadIdx.x;
  const int bm = blockIdx.x >> 3, bn = blockIdx.x & 7;
  const bool iscap = bm < 20;
  const u16* A = iscap ? capb + (size_t)bm * 64 * 1024
                       : imgb + (size_t)(bm - 20) * 64 * 1024;
  const int kofs = iscap ? 0 : 1024;
  const int wv = tid >> 6, lane = tid & 63;
  const int quad = lane >> 4, l15 = lane & 15;
  const int wm = (wv & 1) * 32, wn = (wv >> 1) * 64;

  f32x4 accL[2][4], accG[2][4];
#pragma unroll
  for (int a = 0; a < 2; ++a)
#pragma unroll
    for (int b = 0; b < 4; ++b) {
      accL[a][b] = (f32x4){0.f, 0.f, 0.f, 0.f};
      accG[a][b] = (f32x4){0.f, 0.f, 0.f, 0.f};
    }

  for (int kt = 0; kt < 32; ++kt) {
    if (kt) __syncthreads();
    {  // A: 256 chunks -> 1/thread, XOR-swz source
      const int row = tid >> 2, c8 = tid & 3;
      const int js = c8 ^ (row & 3);
      gl2lds16(A + (size_t)row * 1024 + kt * 32 + js * 8,
               lsA + (size_t)(wv * 64) * 8);
    }
#pragma unroll
    for (int s = 0; s < 2; ++s) {  // B: 512 chunks each
      const int idx = s * 256 + tid;
      const int row = idx >> 2, c8 = idx & 3;
      const int js = c8 ^ (row & 3);
      const size_t bro = (size_t)(bn * 128 + row) * 2048 + kofs + kt * 32 + js * 8;
      gl2lds16(WTl + bro, lsBl + (size_t)(s * 256 + wv * 64) * 8);
      gl2lds16(WTg + bro, lsBg + (size_t)(s * 256 + wv * 64) * 8);
    }
    __syncthreads();
    bf16x8 af[2], bl8[4], bg8[4];
#pragma unroll
    for (int mt = 0; mt < 2; ++mt) {
      const int ra = wm + mt * 16 + l15;
      af[mt] = *(const bf16x8*)(lsA + ra * 32 + (quad ^ (ra & 3)) * 8);
    }
#pragma unroll
    for (int nt = 0; nt < 4; ++nt) {
      const int rb = wn + nt * 16 + l15;
      const int off = rb * 32 + (quad ^ (rb & 3)) * 8;
      bl8[nt] = *(const bf16x8*)(lsBl + off);
      bg8[nt] = *(const bf16x8*)(lsBg + off);
    }
#pragma unroll
    for (int mt = 0; mt < 2; ++mt)
#pragma unroll
      for (int nt = 0; nt < 4; ++nt) {
        accL[mt][nt] = MFMA_BF16(af[mt], bl8[nt], accL[mt][nt]);
        accG[mt][nt] = MFMA_BF16(af[mt], bg8[nt], accG[mt][nt]);
      }
  }
#pragma unroll
  for (int mt = 0; mt < 2; ++mt)
#pragma unroll
    for (int nt = 0; nt < 4; ++nt) {
      const int n = bn * 128 + wn + nt * 16 + l15;
      if (iscap) {
        const float blv = bL[n], bgv = bG[n];
#pragma unroll
        for (int r = 0; r < 4; ++r) {
          const int m = bm * 64 + wm + mt * 16 + quad * 4 + r;
          preL[((size_t)m << 10) + n] = f2bf(accL[mt][nt][r] + blv);
          preG[((size_t)m << 10) + n] = f2bf(accG[mt][nt][r] + bgv);
        }
      } else {
#pragma unroll
        for (int r = 0; r < 4; ++r) {
          const int mi = (bm - 20) * 64 + wm + mt * 16 + quad * 4 + r;
          const int i = (mi * 3641) >> 17;   // floor(mi/36), mi<1152
          const int r36 = mi - i * 36;
          const size_t gb = (((size_t)(i << 10)) + n) * 64 + r36;
          cwTL[gb] = f2bf(accL[mt][nt][r]);
          cwTG[gb] = f2bf(accG[mt][nt][r]);
        }
      }
    }
}

// ---------------------------------------------------------------------------
// Per-image Gram: G[i] = ctx_i @ ctx_i^T [36x36], stored [48][64] bf16 hi+lo.
__global__ __launch_bounds__(256, 2) void gram_k(const u16* __restrict__ imgb,
                                                 u16* __restrict__ Ghi,
                                                 u16* __restrict__ Glo) {
  __shared__ float lsS[48 * 52];
  const int tid = threadIdx.x;
  const int i = blockIdx.x;
  const int wv = tid >> 6, lane = tid & 63;
  const int quad = lane >> 4, l15 = lane & 15;
  for (int k = tid; k < 48 * 52; k += 256) lsS[k] = 0.f;

  const u16* arow[3]; bool avalid[3];
#pragma unroll
  for (int mt = 0; mt < 3; ++mt) {
    const int r = mt * 16 + l15;
    avalid[mt] = r < 36;
    arow[mt] = imgb + ((size_t)(i * 36 + (r < 36 ? r : 35)) << 10);
  }
  const bf16x8 zero8 = {0, 0, 0, 0, 0, 0, 0, 0};
  f32x4 acc[3][3];
#pragma unroll
  for (int a = 0; a < 3; ++a)
#pragma unroll
    for (int b = 0; b < 3; ++b) acc[a][b] = (f32x4){0.f, 0.f, 0.f, 0.f};

  for (int kk = wv * 8; kk < wv * 8 + 8; ++kk) {
    const int ko = kk * 32 + quad * 8;
    bf16x8 af[3];
#pragma unroll
    for (int mt = 0; mt < 3; ++mt)
      af[mt] = avalid[mt] ? *(const bf16x8*)(arow[mt] + ko) : zero8;
#pragma unroll
    for (int mt = 0; mt < 3; ++mt)
#pragma unroll
      for (int nt = 0; nt < 3; ++nt)
        acc[mt][nt] = MFMA_BF16(af[mt], af[nt], acc[mt][nt]);
  }
  __syncthreads();
#pragma unroll
  for (int mt = 0; mt < 3; ++mt)
#pragma unroll
    for (int nt = 0; nt < 3; ++nt)
#pragma unroll
      for (int rg = 0; rg < 4; ++rg)
        atomicAdd(&lsS[(nt * 16 + l15) * 52 + mt * 16 + quad * 4 + rg],
                  acc[mt][nt][rg]);
  __syncthreads();
  if (wv == 0) {
#pragma unroll
    for (int nt = 0; nt < 3; ++nt) {
      const int rp = nt * 16 + l15;  // stored row (G symmetric)
#pragma unroll
      for (int mt = 0; mt < 3; ++mt) {
        const f32x4 g = *(const f32x4*)&lsS[rp * 52 + mt * 16 + quad * 4];
        u16 hv[4], lv[4];
#pragma unroll
        for (int rg = 0; rg < 4; ++rg) {
          hv[rg] = f2bf(g[rg]);
          lv[rg] = f2bf(g[rg] - bf2f(hv[rg]));
        }
        const size_t gb = ((size_t)i * 48 + rp) * 64 + mt * 16 + quad * 4;
        *(uint2*)(Ghi + gb) = *(const uint2*)hv;
        *(uint2*)(Glo + gb) = *(const uint2*)lv;
      }
    }
  }
  for (int k = tid; k < 48 * 16; k += 256) {  // zero cols 48..63
    const size_t gb = ((size_t)i * 48 + (k >> 4)) * 64 + 48 + (k & 15);
    Ghi[gb] = 0; Glo[gb] = 0;
  }
}

// ---------------------------------------------------------------------------
// Batched small-N GEMM: out[i][m][r] = sum_d A[m,d]*ctx_i[r,d], m-tile 128,
// N=48 (r>=36 zero via frag masking), K=1024. A = capb (shared across i).
__global__ __launch_bounds__(256, 4) void s12gemm_k(
    const u16* __restrict__ Abase, const int perI,
    const u16* __restrict__ imgb, float* __restrict__ out) {
  __shared__ __align__(16) u16 lsA[128 * 32];
  __shared__ __align__(16) u16 lsB[64 * 32];
  const int tid = threadIdx.x;
  const int m0 = blockIdx.x * 128;
  const int i = blockIdx.y;
  const int wv = tid >> 6, lane = tid & 63;
  const int quad = lane >> 4, l15 = lane & 15;
  const u16* A = Abase + (perI ? ((size_t)i * 1280 * 1024) : 0);
  const u16* B = imgb + (size_t)i * 36 * 1024;
  const bf16x8 zero8 = {0, 0, 0, 0, 0, 0, 0, 0};

  f32x4 acc[2][3];
#pragma unroll
  for (int a = 0; a < 2; ++a)
#pragma unroll
    for (int b = 0; b < 3; ++b) acc[a][b] = (f32x4){0.f, 0.f, 0.f, 0.f};

  for (int kt = 0; kt < 32; ++kt) {
    if (kt) __syncthreads();
#pragma unroll
    for (int s = 0; s < 2; ++s) {  // A: 512 chunks of 16B
      const int idx = s * 256 + tid;
      const int rr = idx >> 2, j = idx & 3;
      const int js = j ^ ((rr >> 2) & 3);  // bank swizzle
      gl2lds16(A + (size_t)(m0 + rr) * 1024 + kt * 32 + js * 8,
               lsA + (size_t)(s * 256 + wv * 64) * 8);
    }
    {  // B: 256 chunks (64 rows; rows >=36 clamped, masked at frag level)
      const int rr = tid >> 2, j = tid & 3;
      const int rc = rr < 36 ? rr : 35;
      const int js = j ^ ((rr >> 2) & 3);
      gl2lds16(B + (size_t)rc * 1024 + kt * 32 + js * 8,
               lsB + (size_t)(wv * 64) * 8);
    }
    __syncthreads();
    bf16x8 a2[2], b3[3];
#pragma unroll
    for (int mf = 0; mf < 2; ++mf) {
      const int ra = wv * 32 + mf * 16 + l15;
      a2[mf] = *(const bf16x8*)(lsA + ra * 32 + (quad ^ ((ra >> 2) & 3)) * 8);
    }
#pragma unroll
    for (int nf = 0; nf < 3; ++nf) {
      const int rb = nf * 16 + l15;
      const bf16x8 bv = *(const bf16x8*)(lsB + rb * 32 + (quad ^ ((rb >> 2) & 3)) * 8);
      b3[nf] = (rb < 36) ? bv : zero8;
    }
#pragma unroll
    for (int mf = 0; mf < 2; ++mf)
#pragma unroll
      for (int nf = 0; nf < 3; ++nf)
        acc[mf][nf] = MFMA_BF16(a2[mf], b3[nf], acc[mf][nf]);
  }
#pragma unroll
  for (int mf = 0; mf < 2; ++mf)
#pragma unroll
    for (int nf = 0; nf < 3; ++nf)
#pragma unroll
      for (int rg = 0; rg < 4; ++rg) {
        const int m = m0 + wv * 32 + mf * 16 + quad * 4 + rg;
        out[((size_t)i * 1280 + m) * 48 + nf * 16 + l15] = acc[mf][nf][rg];
      }
}

// ---------------------------------------------------------------------------
// Fused gate + S2: per (64-ct tile, image i) block.
// Loop 8 d-chunks of 128: stage cwT chunk -> gate GEMM (A=cwT rows d,
// B=P1 rows ct, K=64) -> gating epilogue -> q2 chunk into padded LDS ->
// S2 += ctx@q2chunk^T. S2[i][ct][48] fp32 out.
__global__ __launch_bounds__(256, 2) void gates2_k(
    const u16* __restrict__ cwTL, const u16* __restrict__ cwTG,
    const u16* __restrict__ P1, const u16* __restrict__ preL,
    const u16* __restrict__ preG, const u16* __restrict__ capb,
    const u16* __restrict__ imgb, float* __restrict__ S2) {
  __shared__ __align__(16) u16 lsP[64 * 64];    // P1 tile [ct][64r] XOR-swz
  __shared__ __align__(16) u16 lsCl[128 * 64];  // cwT chunk [d][64r] XOR-swz
  __shared__ __align__(16) u16 lsCg[128 * 64];
  __shared__ __align__(16) u16 lsQ[64 * 136];   // q2 chunk [ct][128d], pad 136

  const int tid = threadIdx.x;
  const int bid = blockIdx.x;
  const int i = bid & 31, ctt = bid >> 5;  // i fastest: image i -> XCD i%8
  const int ct0 = ctt * 64;
  const int wv = tid >> 6, lane = tid & 63;
  const int quad = lane >> 4, l15 = lane & 15;
  const int wd = (wv & 1) * 64, wc = (wv >> 1) * 32;

  // stage P1 tile: 512 chunks -> 2/thread (XOR-swz source, linear dest)
#pragma unroll
  for (int s = 0; s < 2; ++s) {
    const int idx = s * 256 + tid;
    const int rr = idx >> 3, j = idx & 7;
    const int js = j ^ (rr & 7);
    gl2lds16(P1 + ((size_t)i * 1280 + ct0 + rr) * 64 + js * 8,
             lsP + (size_t)(s * 256 + wv * 64) * 8);
  }

  const u16* arow[3]; bool avalid[3];
#pragma unroll
  for (int mt = 0; mt < 3; ++mt) {
    const int r = mt * 16 + l15;
    avalid[mt] = r < 36;
    arow[mt] = imgb + ((size_t)(i * 36 + (r < 36 ? r : 35)) << 10);
  }
  const bf16x8 zero8 = {0, 0, 0, 0, 0, 0, 0, 0};

  f32x4 acc2[3];
  acc2[0] = acc2[1] = acc2[2] = (f32x4){0.f, 0.f, 0.f, 0.f};

  for (int dc = 0; dc < 8; ++dc) {
    // stage cwT chunk [128 d][64 r]: 1024 chunks x2 -> 4/thread each
#pragma unroll
    for (int s = 0; s < 4; ++s) {
      const int idx = s * 256 + tid;
      const int rr = idx >> 3, j = idx & 7;
      const int js = j ^ (rr & 7);
      const size_t gsrc = ((size_t)(i << 10) + dc * 128 + rr) * 64 + js * 8;
      const size_t dofs = (size_t)(s * 256 + wv * 64) * 8;
      gl2lds16(cwTL + gsrc, lsCl + dofs);
      gl2lds16(cwTG + gsrc, lsCg + dofs);
    }
    __syncthreads();  // staging visible; prev-chunk lsQ readers done

    // ---- gate GEMM: wave covers 64 d (wd) x 32 ct (wc)
    f32x4 accL[4][2], accG[4][2];
#pragma unroll
    for (int a = 0; a < 4; ++a)
#pragma unroll
      for (int b = 0; b < 2; ++b) {
        accL[a][b] = (f32x4){0.f, 0.f, 0.f, 0.f};
        accG[a][b] = (f32x4){0.f, 0.f, 0.f, 0.f};
      }
    bf16x8 bp[2][2];
#pragma unroll
    for (int nt = 0; nt < 2; ++nt) {
      const int rb = wc + nt * 16 + l15;
#pragma unroll
      for (int ks = 0; ks < 2; ++ks)
        bp[nt][ks] =
            *(const bf16x8*)(lsP + rb * 64 + (((ks * 4 + quad) ^ (rb & 7)) * 8));
    }
#pragma unroll
    for (int mt = 0; mt < 4; ++mt) {
      const int ra = wd + mt * 16 + l15;
#pragma unroll
      for (int ks = 0; ks < 2; ++ks) {
        const int off = ra * 64 + (((ks * 4 + quad) ^ (ra & 7)) * 8);
        const bf16x8 al = *(const bf16x8*)(lsCl + off);
        const bf16x8 ag = *(const bf16x8*)(lsCg + off);
#pragma unroll
        for (int nt = 0; nt < 2; ++nt) {
          accL[mt][nt] = MFMA_BF16(al, bp[nt][ks], accL[mt][nt]);
          accG[mt][nt] = MFMA_BF16(ag, bp[nt][ks], accG[mt][nt]);
        }
      }
    }
    // ---- gating epilogue: lane holds 4 consecutive d for one ct
#pragma unroll
    for (int mt = 0; mt < 4; ++mt) {
      const int drel = wd + mt * 16 + quad * 4;
      const int D0 = dc * 128 + drel;
#pragma unroll
      for (int nt = 0; nt < 2; ++nt) {
        const int ctL = wc + nt * 16 + l15;
        const size_t rb = (((size_t)(ct0 + ctL)) << 10) + D0;
        const uint2 plv = *(const uint2*)(preL + rb);
        const uint2 pgv = *(const uint2*)(preG + rb);
        const uint2 cfv = *(const uint2*)(capb + rb);
        const float pl4[4] = {bf2f((u16)(plv.x & 0xffffu)), bf2f((u16)(plv.x >> 16)),
                              bf2f((u16)(plv.y & 0xffffu)), bf2f((u16)(plv.y >> 16))};
        const float pg4[4] = {bf2f((u16)(pgv.x & 0xffffu)), bf2f((u16)(pgv.x >> 16)),
                              bf2f((u16)(pgv.y & 0xffffu)), bf2f((u16)(pgv.y >> 16))};
        const float cf4[4] = {bf2f((u16)(cfv.x & 0xffffu)), bf2f((u16)(cfv.x >> 16)),
                              bf2f((u16)(cfv.y & 0xffffu)), bf2f((u16)(cfv.y >> 16))};
        u16 ov[4];
#pragma unroll
        for (int rg = 0; rg < 4; ++rg) {
          const float aL = accL[mt][nt][rg] + pl4[rg];
          const float aG = accG[mt][nt][rg] + pg4[rg];
          const float g = frcp(1.f + __expf(-aG));
          const float u = 2.f * frcp(1.f + __expf(-2.f * aL)) - 1.f;  // tanh
          ov[rg] = f2bf(cf4[rg] * g + u * (1.f - g));
        }
        *(uint2*)(lsQ + ctL * 136 + drel) = *(const uint2*)ov;
      }
    }
    __syncthreads();  // q2 chunk visible

    // ---- S2 partial: wave owns ct group wv*16..+15, K = this d-chunk (128)
#pragma unroll
    for (int ks = 0; ks < 4; ++ks) {
      const int dg = dc * 128 + ks * 32 + quad * 8;
      const bf16x8 bq =
          *(const bf16x8*)(lsQ + (wv * 16 + l15) * 136 + ks * 32 + quad * 8);
#pragma unroll
      for (int mt = 0; mt < 3; ++mt) {
        const bf16x8 af = avalid[mt] ? *(const bf16x8*)(arow[mt] + dg) : zero8;
        acc2[mt] = MFMA_BF16(af, bq, acc2[mt]);
      }
    }
  }
  const int ctg = ct0 + wv * 16 + l15;
#pragma unroll
  for (int mt = 0; mt < 3; ++mt)
    *(f32x4*)(S2 + ((size_t)i * 1280 + ctg) * 48 + mt * 16 + quad * 4) = acc2[mt];
}

// ---------------------------------------------------------------------------
// Per-pair scoring (4 pairs/block, one per wave). Softmax(Ssm) -> P;
// pn = sum P*S1; pw = P^T G P; sim = mean cosine. PASS2=0 also writes P1+sim1;
// PASS2=1 writes score = sim1 + sim2.
template <int PASS2>
__global__ __launch_bounds__(256, 2) void score_k(
    const float* __restrict__ Ssm, const float* __restrict__ S1,
    const u16* __restrict__ Ghi, const u16* __restrict__ Glo,
    const float* __restrict__ cnorm, u16* __restrict__ P1,
    float* __restrict__ sim1, float* __restrict__ score) {
  __shared__ __align__(16) u16 lsP[4][48 * 72];
  const int tid = threadIdx.x;
  const int wv = tid >> 6, lane = tid & 63;
  const int quad = lane >> 4, l15 = lane & 15;
  const int pair = blockIdx.x * 4 + wv;
  const int c = pair >> 5, i = pair & 31;
  u16* lsPw = lsP[wv];
  for (int k = lane; k < 1728; k += 64) ((unsigned*)lsPw)[k] = 0u;

  float sS[3][3][4], s1f[3][3][4];
  const float* Sb = Ssm + ((size_t)i * 1280 + c * 40) * 48;
  const float* S1b = S1 + ((size_t)i * 1280 + c * 40) * 48;
#pragma unroll
  for (int nt = 0; nt < 3; ++nt) {
    const int t = nt * 16 + l15;
    const int tr = t < 40 ? t : 39;
#pragma unroll
    for (int mt = 0; mt < 3; ++mt) {
      f32x4 v = *(const f32x4*)(Sb + (size_t)tr * 48 + mt * 16 + quad * 4);
      if (t >= 40) v = (f32x4){0.f, 0.f, 0.f, 0.f};  // keep l2norm-over-t exact
#pragma unroll
      for (int rg = 0; rg < 4; ++rg) sS[mt][nt][rg] = v[rg];
      if (PASS2) {
        const f32x4 w = *(const f32x4*)(S1b + (size_t)tr * 48 + mt * 16 + quad * 4);
#pragma unroll
        for (int rg = 0; rg < 4; ++rg) s1f[mt][nt][rg] = w[rg];
      } else {
#pragma unroll
        for (int rg = 0; rg < 4; ++rg) s1f[mt][nt][rg] = v[rg];
      }
    }
  }

  // ---- leaky + l2norm over t, temperature softmax over r (in-register)
  float rn[3][4];
#pragma unroll
  for (int mt = 0; mt < 3; ++mt)
#pragma unroll
    for (int rg = 0; rg < 4; ++rg) {
      float s2 = 0.f;
#pragma unroll
      for (int nt = 0; nt < 3; ++nt) {
        float v = sS[mt][nt][rg]; v = v > 0.f ? v : 0.1f * v; s2 += v * v;
      }
      s2 += __shfl_xor(s2, 1, 64); s2 += __shfl_xor(s2, 2, 64);
      s2 += __shfl_xor(s2, 4, 64); s2 += __shfl_xor(s2, 8, 64);
      rn[mt][rg] = sqrtf(s2) + 1e-8f;
    }
  float mx[3] = {-3.0e38f, -3.0e38f, -3.0e38f};
#pragma unroll
  for (int mt = 0; mt < 3; ++mt)
#pragma unroll
    for (int nt = 0; nt < 3; ++nt)
#pragma unroll
      for (int rg = 0; rg < 4; ++rg) {
        const int r = mt * 16 + quad * 4 + rg;
        float v = sS[mt][nt][rg]; v = v > 0.f ? v : 0.1f * v;
        float zz = 9.f * v / rn[mt][rg];
        zz = (r < 36) ? zz : -3.0e38f;
        sS[mt][nt][rg] = zz;
        mx[nt] = fmaxf(mx[nt], zz);
      }
#pragma unroll
  for (int nt = 0; nt < 3; ++nt) {
    mx[nt] = fmaxf(mx[nt], __shfl_xor(mx[nt], 16, 64));
    mx[nt] = fmaxf(mx[nt], __shfl_xor(mx[nt], 32, 64));
  }
  float ss[3] = {0.f, 0.f, 0.f};
#pragma unroll
  for (int mt = 0; mt < 3; ++mt)
#pragma unroll
    for (int nt = 0; nt < 3; ++nt)
#pragma unroll
      for (int rg = 0; rg < 4; ++rg) {
        const float e = __expf(sS[mt][nt][rg] - mx[nt]);
        sS[mt][nt][rg] = e; ss[nt] += e;
      }
#pragma unroll
  for (int nt = 0; nt < 3; ++nt) {
    ss[nt] += __shfl_xor(ss[nt], 16, 64);
    ss[nt] += __shfl_xor(ss[nt], 32, 64);
    ss[nt] = 1.f / ss[nt];
  }
#pragma unroll
  for (int nt = 0; nt < 3; ++nt) {
    const int t = nt * 16 + l15;
#pragma unroll
    for (int mt = 0; mt < 3; ++mt) {
#pragma unroll
      for (int rg = 0; rg < 4; ++rg) sS[mt][nt][rg] *= ss[nt];
      if (t < 40) {
        u16 pv[4];
#pragma unroll
        for (int rg = 0; rg < 4; ++rg) pv[rg] = f2bf(sS[mt][nt][rg]);
        *(uint2*)(lsPw + t * 72 + mt * 16 + quad * 4) = *(const uint2*)pv;
      }
    }
  }

  // ---- pn = sum_r P * S1raw (per t)
  float pnv[3] = {0.f, 0.f, 0.f};
#pragma unroll
  for (int nt = 0; nt < 3; ++nt)
#pragma unroll
    for (int mt = 0; mt < 3; ++mt)
#pragma unroll
      for (int rg = 0; rg < 4; ++rg) pnv[nt] += sS[mt][nt][rg] * s1f[mt][nt][rg];

  // ---- P1 global write (GEMM operand layout, stride 64, zeros beyond r=36)
  if (!PASS2) {
    for (int idx = lane; idx < 320; idx += 64) {
      const int t = idx >> 3, j = idx & 7;
      *(uint4*)(P1 + ((size_t)i * 1280 + c * 40 + t) * 64 + j * 8) =
          *(const uint4*)(lsPw + t * 72 + j * 8);
    }
  }

  // ---- pw = P^T G P via Gram MFMA
  bf16x8 afA[3][2];
#pragma unroll
  for (int mtT = 0; mtT < 3; ++mtT)
#pragma unroll
    for (int ks = 0; ks < 2; ++ks)
      afA[mtT][ks] =
          *(const bf16x8*)(lsPw + (mtT * 16 + l15) * 72 + ks * 32 + quad * 8);
  f32x4 gp[3][3];
#pragma unroll
  for (int a = 0; a < 3; ++a)
#pragma unroll
    for (int b = 0; b < 3; ++b) gp[a][b] = (f32x4){0.f, 0.f, 0.f, 0.f};
#pragma unroll
  for (int ks = 0; ks < 2; ++ks)
#pragma unroll
    for (int mtG = 0; mtG < 3; ++mtG) {
      const size_t gb = ((size_t)i * 48 + mtG * 16 + l15) * 64 + ks * 32 + quad * 8;
      const bf16x8 gh = *(const bf16x8*)(Ghi + gb);
      const bf16x8 gl = *(const bf16x8*)(Glo + gb);
#pragma unroll
      for (int mtT = 0; mtT < 3; ++mtT) {
        gp[mtG][mtT] = MFMA_BF16(gh, afA[mtT][ks], gp[mtG][mtT]);
        gp[mtG][mtT] = MFMA_BF16(gl, afA[mtT][ks], gp[mtG][mtT]);
      }
    }
  float pwv[3] = {0.f, 0.f, 0.f};
#pragma unroll
  for (int nt = 0; nt < 3; ++nt)
#pragma unroll
    for (int mt = 0; mt < 3; ++mt)
#pragma unroll
      for (int rg = 0; rg < 4; ++rg)
        pwv[nt] += sS[mt][nt][rg] * gp[mt][nt][rg];
#pragma unroll
  for (int nt = 0; nt < 3; ++nt) {
    pnv[nt] += __shfl_xor(pnv[nt], 16, 64); pnv[nt] += __shfl_xor(pnv[nt], 32, 64);
    pwv[nt] += __shfl_xor(pwv[nt], 16, 64); pwv[nt] += __shfl_xor(pwv[nt], 32, 64);
  }
  float tot = 0.f;
#pragma unroll
  for (int nt = 0; nt < 3; ++nt) {
    const int t = nt * 16 + l15;
    if (t < 40) {
      const float w2 = sqrtf(fmaxf(pwv[nt], 0.f));
      tot += pnv[nt] / fmaxf(cnorm[c * 40 + t] * w2, 1e-8f);
    }
  }
  tot += __shfl_xor(tot, 1, 64); tot += __shfl_xor(tot, 2, 64);
  tot += __shfl_xor(tot, 4, 64); tot += __shfl_xor(tot, 8, 64);
  if (lane == 0) {
    const float s = tot * (1.f / 40.f);
    if (PASS2) score[i * 32 + c] = sim1[pair] + s;
    else sim1[pair] = s;
  }
}

// ---------------------------------------------------------------------------
extern "C" void kernel_launch(void* const* d_in, const int* in_sizes, int n_in,
                              void* d_out, int out_size, void* d_ws, size_t ws_size,
                              hipStream_t stream) {
  const float* img = (const float*)d_in[0];   // [32][36][1024] fp32
  const float* cap = (const float*)d_in[1];   // [32][40][1024] fp32
  const float* Wl  = (const float*)d_in[2];   // [2048][1024] fp32
  const float* bl  = (const float*)d_in[3];   // [1024] fp32
  const float* Wg  = (const float*)d_in[4];
  const float* bg  = (const float*)d_in[5];
  float* out = (float*)d_out;                 // [32][32] fp32

  char* ws = (char*)d_ws;
  float* cnrm = (float*)ws;               ws += 5120;
  float* sim1 = (float*)ws;               ws += 4096;
  u16*   WTl  = (u16*)ws;                 ws += (size_t)1024 * 2048 * 2;   // 4.2 MB
  u16*   WTg  = (u16*)ws;                 ws += (size_t)1024 * 2048 * 2;   // 4.2 MB
  u16*   preL = (u16*)ws;                 ws += (size_t)1280 * 1024 * 2;   // 2.6 MB
  u16*   preG = (u16*)ws;                 ws += (size_t)1280 * 1024 * 2;   // 2.6 MB
  u16*   capb = (u16*)ws;                 ws += (size_t)1280 * 1024 * 2;   // 2.6 MB
  u16*   imgb = (u16*)ws;                 ws += (size_t)1152 * 1024 * 2;   // 2.4 MB
  u16*   Ghi  = (u16*)ws;                 ws += (size_t)32 * 48 * 64 * 2;  // 196 KB
  u16*   Glo  = (u16*)ws;                 ws += (size_t)32 * 48 * 64 * 2;  // 196 KB
  u16*   cwTL = (u16*)ws;                 ws += (size_t)32 * 1024 * 64 * 2;  // 4.2 MB
  u16*   cwTG = (u16*)ws;                 ws += (size_t)32 * 1024 * 64 * 2;  // 4.2 MB
  float* S1   = (float*)ws;               ws += (size_t)32 * 1280 * 48 * 4;  // 7.9 MB
  float* S2   = (float*)ws;               ws += (size_t)32 * 1280 * 48 * 4;  // 7.9 MB
  u16*   P1   = (u16*)ws;                 ws += (size_t)32 * 1280 * 64 * 2;  // 5.2 MB

  cvt_k<<<1152, 256, 0, stream>>>(img, imgb);
  cvt_k<<<1280, 256, 0, stream>>>(cap, capb);
  transpose_k<<<dim3(64, 32, 2), dim3(32, 8), 0, stream>>>(Wl, Wg, WTl, WTg);
  capnorm_k<<<320, 256, 0, stream>>>(cap, cnrm);
  gram_k<<<32, 256, 0, stream>>>(imgb, Ghi, Glo);
  zero_k<<<2048, 256, 0, stream>>>(cwTL);  // cwTL+cwTG contiguous: 8.4 MB
  gemmw_k<<<304, 256, 0, stream>>>(capb, imgb, WTl, WTg, preL, preG,
                                   cwTL, cwTG, bl, bg);
  s12gemm_k<<<dim3(10, 32), 256, 0, stream>>>(capb, 0, imgb, S1);
  score_k<0><<<256, 256, 0, stream>>>(S1, S1, Ghi, Glo, cnrm, P1, sim1, out);
  gates2_k<<<640, 256, 0, stream>>>(cwTL, cwTG, P1, preL, preG, capb, imgb, S2);
  score_k<1><<<256, 256, 0, stream>>>(S2, S1, Ghi, Glo, cnrm, P1, sim1, out);
}